// Round 5
// baseline (28208.865 us; speedup 1.0000x reference)
//
#include <hip/hip_runtime.h>
#include <math.h>

#define Bb 256
#define Ii 128
#define Tt 256
#define Hh 512
#define Oo 2
#define TBr (Tt*Bb)
#define EPS_BN 1e-5f

typedef __attribute__((ext_vector_type(8))) short short8;
typedef __attribute__((ext_vector_type(8))) __bf16 bf16x8;
typedef __attribute__((ext_vector_type(4))) float f32x4;

__device__ __forceinline__ f32x4 mfma_bf16(short8 a, short8 b, f32x4 c) {
    return __builtin_amdgcn_mfma_f32_16x16x32_bf16(
        __builtin_bit_cast(bf16x8, a), __builtin_bit_cast(bf16x8, b), c, 0, 0, 0);
}
__device__ __forceinline__ short f2bf(float f) {
    union { float f; unsigned u; } v; v.f = f;
    unsigned r = (v.u + 0x7FFFu + ((v.u >> 16) & 1u)) >> 16;
    return (short)r;
}
__device__ __forceinline__ float bf2f(short s) {
    union { unsigned u; float f; } v; v.u = ((unsigned)(unsigned short)s) << 16;
    return v.f;
}
__device__ __forceinline__ float sigmoidf_(float x) { return 1.f / (1.f + expf(-x)); }
__device__ __forceinline__ float softplusf_(float x) { return fmaxf(x, 0.f) + log1pf(expf(-fabsf(x))); }

// ---------------------------------------------------------------------------
// repack: input [B,3,I,T] fp32 -> time-major X fp32 [T,B,I], M bf16, D bf16
// ---------------------------------------------------------------------------
__global__ __launch_bounds__(1024) void repack_kernel(const float* __restrict__ in,
                                                      float* __restrict__ Xall,
                                                      short* __restrict__ Mall,
                                                      short* __restrict__ Dall)
{
    __shared__ float tile[32][33];
    const int bz = blockIdx.z;
    const int b = bz / 3, cch = bz % 3;
    const int t0 = blockIdx.x * 32, i0 = blockIdx.y * 32;
    const int tx = threadIdx.x, ty = threadIdx.y;
    const float* src = in + ((size_t)b * 3 + cch) * (size_t)Ii * Tt;
    tile[ty][tx] = src[(size_t)(i0 + ty) * Tt + t0 + tx];
    __syncthreads();
    const float v = tile[tx][ty];
    const size_t off = ((size_t)(t0 + ty) * Bb + b) * Ii + i0 + tx;
    if (cch == 0)      Xall[off] = v;
    else if (cch == 1) Mall[off] = f2bf(v);
    else               Dall[off] = f2bf(v);
}

// ---------------------------------------------------------------------------
// pack weights -> bf16 transposed (n-major, k rows) for MFMA fragments
// ---------------------------------------------------------------------------
__global__ __launch_bounds__(256) void pack_weights_kernel(
    const float* __restrict__ W_dg_x, const float* __restrict__ W_dg_h,
    const float* __restrict__ W_xz, const float* __restrict__ W_hz, const float* __restrict__ W_mz, const float* __restrict__ b_z,
    const float* __restrict__ W_xr, const float* __restrict__ W_hr, const float* __restrict__ W_mr, const float* __restrict__ b_r,
    const float* __restrict__ W_xh, const float* __restrict__ W_hh, const float* __restrict__ W_mh,
    short* __restrict__ Wc1T, short* __restrict__ Wc2T,
    short* __restrict__ WdgxT, short* __restrict__ WdghT, float* __restrict__ bias1)
{
    const int idx = blockIdx.x * blockDim.x + threadIdx.x;
    const int n1 = 1024 * 768, n2 = 512 * 768, n3 = 128 * 128, n4 = 512 * 128;
    if (idx < n1) {
        const int n = idx / 768, k = idx % 768;
        const int col = (n < Hh) ? n : (n - Hh);
        const float* Wx = (n < Hh) ? W_xz : W_xr;
        const float* Wm = (n < Hh) ? W_mz : W_mr;
        const float* Wh = (n < Hh) ? W_hz : W_hr;
        float v;
        if (k < Ii)        v = Wx[(size_t)k * Hh + col];
        else if (k < 2*Ii) v = Wm[(size_t)(k - Ii) * Hh + col];
        else               v = Wh[(size_t)(k - 2*Ii) * Hh + col];
        Wc1T[idx] = f2bf(v);
    } else if (idx < n1 + n2) {
        const int j = idx - n1;
        const int n = j / 768, k = j % 768;
        float v;
        if (k < Ii)        v = W_xh[(size_t)k * Hh + n];
        else if (k < 2*Ii) v = W_mh[(size_t)(k - Ii) * Hh + n];
        else               v = W_hh[(size_t)(k - 2*Ii) * Hh + n];
        Wc2T[j] = f2bf(v);
    } else if (idx < n1 + n2 + n3) {
        const int j = idx - n1 - n2;
        const int n = j >> 7, k = j & 127;
        WdgxT[j] = f2bf(W_dg_x[(size_t)k * Ii + n]);
    } else if (idx < n1 + n2 + n3 + n4) {
        const int j = idx - n1 - n2 - n3;
        const int n = j >> 7, k = j & 127;
        WdghT[j] = f2bf(W_dg_h[(size_t)k * Hh + n]);
    } else if (idx < n1 + n2 + n3 + n4 + 1024) {
        const int n = idx - n1 - n2 - n3 - n4;
        bias1[n] = (n < Hh) ? b_z[n] : b_r[n - Hh];
    }
}

// ---------------------------------------------------------------------------
// gdecay: C = bf16(exp(-relu(A @ B + bias)))  A bf16 [M][128], BT bf16 [N][128]
// ---------------------------------------------------------------------------
__global__ __launch_bounds__(64) void gdecay_kernel(const short* __restrict__ A,
                                                    const short* __restrict__ BT,
                                                    const float* __restrict__ bias,
                                                    short* __restrict__ C, int N)
{
    const int lane = threadIdx.x;
    const int c = lane & 15, g = lane >> 4;
    const int m0 = blockIdx.x * 32, n0 = blockIdx.y * 64;
    const short* a0 = A + (size_t)(m0 + c) * Ii + 8 * g;
    const short* a1 = a0 + (size_t)16 * Ii;
    const short* bw = BT + (size_t)(n0 + c) * Ii + 8 * g;
    f32x4 acc[2][4];
    #pragma unroll
    for (int i = 0; i < 2; ++i)
        #pragma unroll
        for (int f = 0; f < 4; ++f) acc[i][f] = (f32x4){0.f, 0.f, 0.f, 0.f};
    #pragma unroll
    for (int k0 = 0; k0 < 128; k0 += 32) {
        const short8 av0 = *(const short8*)(a0 + k0);
        const short8 av1 = *(const short8*)(a1 + k0);
        #pragma unroll
        for (int fn = 0; fn < 4; ++fn) {
            const short8 bv = *(const short8*)(bw + (size_t)fn * 16 * Ii + k0);
            acc[0][fn] = mfma_bf16(av0, bv, acc[0][fn]);
            acc[1][fn] = mfma_bf16(av1, bv, acc[1][fn]);
        }
    }
    #pragma unroll
    for (int fn = 0; fn < 4; ++fn) {
        const int n = n0 + fn * 16 + c;
        const float bs = bias[n];
        #pragma unroll
        for (int fm = 0; fm < 2; ++fm) {
            #pragma unroll
            for (int j = 0; j < 4; ++j) {
                const int m = m0 + fm * 16 + 4 * g + j;
                const float v = expf(-fmaxf(acc[fm][fn][j] + bs, 0.f));
                C[(size_t)m * N + n] = f2bf(v);
            }
        }
    }
}

// ---------------------------------------------------------------------------
// x_last scan + x_eff -> Xe bf16 [T,B,I]
// ---------------------------------------------------------------------------
__global__ __launch_bounds__(256) void xeff_scan_kernel(const float* __restrict__ Xall,
                                                        const short* __restrict__ Mall,
                                                        const short* __restrict__ Gx,
                                                        const float* __restrict__ xmean_p,
                                                        short* __restrict__ Xe)
{
    const int bi = blockIdx.x * blockDim.x + threadIdx.x;
    if (bi >= Bb * Ii) return;
    const float xm = xmean_p[0];
    float xl = 0.f;
    for (int t = 0; t < Tt; ++t) {
        const size_t off = (size_t)t * Bb * Ii + bi;
        const float x = Xall[off];
        const float m = bf2f(Mall[off]);
        const float gx = bf2f(Gx[off]);
        if (m > 0.f) xl = x;
        Xe[off] = f2bf(m * x + (1.f - m) * (gx * xl + (1.f - gx) * xm));
    }
}

// ---------------------------------------------------------------------------
// persistent: 16 blocks x 512 threads. Block owns batch rows [bid*16, +16).
// Everything per-step lives in LDS; only BN partials cross blocks, via
// coherent (sc0sc1) atomic stores/loads -> fence-free device barrier.
// ---------------------------------------------------------------------------
#define SROW_STRIDE 776     // shorts per row of [Xe|Ma|hp] panel (768 + 8 pad)
#define SRH_STRIDE  520     // shorts per row of RH panel (512 + 8 pad)
#define SHR_STRIDE  516     // floats per row of hraw panel (512 + 4 pad)

__global__ __launch_bounds__(512, 2) void grud_persistent(
    const short* __restrict__ Xe, const short* __restrict__ Ma,
    const short* __restrict__ Ghb,
    const short* __restrict__ Wc1T, const short* __restrict__ Wc2T,
    const float* __restrict__ bias1, const float* __restrict__ b_h,
    const float* __restrict__ bn_g, const float* __restrict__ bn_b,
    const float* __restrict__ Why, const float* __restrict__ bhy,
    float* __restrict__ Pst,          // [2][2][16][512] f32 (coherent only)
    int* __restrict__ flags,          // [16][32] ints (coherent only)
    float* __restrict__ out_hs, float* __restrict__ out_ys)
{
    const int bid = blockIdx.x, tid = threadIdx.x;
    const int w = tid >> 6, lane = tid & 63, c = lane & 15, g = lane >> 4;
    const int m0 = bid * 16;

    __shared__ short sROW[16 * SROW_STRIDE];   // 24.8 KB  [row][Xe|Ma|hp]
    __shared__ short sRH [16 * SRH_STRIDE];    // 16.6 KB  [row][r*hp]
    __shared__ float szb [512 * 16];           // 32 KB    [col][row] z
    __shared__ float shraw[16 * SHR_STRIDE];   // 33 KB    [row][col] h_raw
    __shared__ float scs[512], shs[512];       // 4 KB BN scale/shift
    __shared__ float sbias[1024], sbh[512], sWhy[1024];   // 10 KB consts

    // stage constants once
    sbias[tid] = bias1[tid]; sbias[tid + 512] = bias1[tid + 512];
    sbh[tid] = b_h[tid];
    sWhy[tid] = Why[tid]; sWhy[tid + 512] = Why[tid + 512];
    const float bhy0 = bhy[0], bhy1 = bhy[1];
    __syncthreads();

    for (int t = 0; t < Tt; ++t) {
        const int parP = (t - 1) & 1;

        // ---- BN stats from partials(t-1) (coherent loads) ----
        if (t > 0) {
            const int n = tid;
            float s1 = 0.f, s2 = 0.f;
            #pragma unroll
            for (int j = 0; j < 16; ++j) {
                s1 += __hip_atomic_load(&Pst[((size_t)(parP * 2 + 0) * 16 + j) * 512 + n],
                                        __ATOMIC_RELAXED, __HIP_MEMORY_SCOPE_AGENT);
                s2 += __hip_atomic_load(&Pst[((size_t)(parP * 2 + 1) * 16 + j) * 512 + n],
                                        __ATOMIC_RELAXED, __HIP_MEMORY_SCOPE_AGENT);
            }
            const float mu = s1 * (1.f / 256.f);
            const float var = fmaxf(s2 * (1.f / 256.f) - mu * mu, 0.f);
            const float sc = bn_g[n] * rsqrtf(var + EPS_BN);
            scs[n] = sc; shs[n] = bn_b[n] - mu * sc;
            __syncthreads();

            // ---- out_hs / out_ys for t-1 (2 rows per wave) ----
            #pragma unroll
            for (int rr = 0; rr < 2; ++rr) {
                const int r = 2 * w + rr;
                float p0 = 0.f, p1 = 0.f;
                #pragma unroll
                for (int i = 0; i < 8; ++i) {
                    const int nn = lane + 64 * i;
                    const float h = fmaf(shraw[r * SHR_STRIDE + nn], scs[nn], shs[nn]);
                    out_hs[((size_t)(m0 + r) * Tt + (t - 1)) * Hh + nn] = h;
                    p0 += h * sWhy[2 * nn]; p1 += h * sWhy[2 * nn + 1];
                }
                #pragma unroll
                for (int s = 1; s < 64; s <<= 1) { p0 += __shfl_xor(p0, s); p1 += __shfl_xor(p1, s); }
                if (lane == 0) {
                    out_ys[((size_t)(m0 + r) * Tt + (t - 1)) * Oo + 0] = softplusf_(p0 + bhy0);
                    out_ys[((size_t)(m0 + r) * Tt + (t - 1)) * Oo + 1] = softplusf_(p1 + bhy1);
                }
            }
        }

        // ---- stage [Xe|Ma] (cols 0..255) ----
        {
            const int r = tid >> 5, c8 = (tid & 31) * 8;
            const short* src = (c8 < 128)
                ? (Xe + ((size_t)t * Bb + m0 + r) * Ii + c8)
                : (Ma + ((size_t)t * Bb + m0 + r) * Ii + (c8 - 128));
            *(short8*)(&sROW[r * SROW_STRIDE + c8]) = *(const short8*)src;
        }
        // ---- stage hp = BN(hraw(t-1)) * gamma_h(t)  (cols 256..767) ----
        {
            const int r = tid >> 5, n00 = (tid & 31) * 2;
            if (t > 0) {
                const short* gh = Ghb + ((size_t)t * Bb + m0 + r) * Hh;
                #pragma unroll
                for (int i = 0; i < 8; ++i) {
                    const int n = n00 + 64 * i;
                    const unsigned gv = *(const unsigned*)(gh + n);
                    const float g0 = bf2f((short)(gv & 0xffffu));
                    const float g1 = bf2f((short)(gv >> 16));
                    const float h0 = fmaf(shraw[r * SHR_STRIDE + n],     scs[n],     shs[n]);
                    const float h1 = fmaf(shraw[r * SHR_STRIDE + n + 1], scs[n + 1], shs[n + 1]);
                    const unsigned pk = (unsigned)(unsigned short)f2bf(h0 * g0)
                                      | ((unsigned)(unsigned short)f2bf(h1 * g1) << 16);
                    *(unsigned*)(&sROW[r * SROW_STRIDE + 256 + n]) = pk;
                }
            } else {
                #pragma unroll
                for (int i = 0; i < 8; ++i)
                    *(unsigned*)(&sROW[r * SROW_STRIDE + 256 + n00 + 64 * i]) = 0u;
            }
        }
        __syncthreads();

        // ================= Phase A: [Xe|Ma|hp] @ Wc1 (wave: 8 col-tiles) ====
        f32x4 acc[8];
        #pragma unroll
        for (int i = 0; i < 8; ++i) acc[i] = (f32x4){0.f, 0.f, 0.f, 0.f};
        #pragma unroll
        for (int half = 0; half < 2; ++half) {
            short8 bfr[12];
            #pragma unroll
            for (int s = 0; s < 12; ++s)
                bfr[s] = *(const short8*)(&sROW[c * SROW_STRIDE + (half * 12 + s) * 32 + 8 * g]);
            const short* wbase = Wc1T + (size_t)(w * 128 + c) * 768 + half * 384 + 8 * g;
            #pragma unroll
            for (int s = 0; s < 12; ++s) {
                #pragma unroll
                for (int ct = 0; ct < 8; ++ct) {
                    const short8 wf = *(const short8*)(wbase + (size_t)ct * 16 * 768 + 32 * s);
                    acc[ct] = mfma_bf16(wf, bfr[s], acc[ct]);
                }
            }
        }
        // epilogue A: lane c = batch row, 4g+j = weight col within tile
        {
            const bool isz = (w < 4);
            #pragma unroll
            for (int ct = 0; ct < 8; ++ct) {
                #pragma unroll
                for (int j = 0; j < 4; ++j) {
                    const int col = w * 128 + ct * 16 + 4 * g + j;
                    const float v = sigmoidf_(acc[ct][j] + sbias[col]);
                    if (isz) {
                        szb[col * 16 + c] = v;
                    } else {
                        const int nn = col - 512;
                        const float hp = bf2f(sROW[c * SROW_STRIDE + 256 + nn]);
                        sRH[c * SRH_STRIDE + nn] = f2bf(v * hp);
                    }
                }
            }
        }
        __syncthreads();

        // ================= Phase B: [Xe|Ma|RH] @ Wc2 (wave: 4 col-tiles) ====
        f32x4 acc2[4];
        #pragma unroll
        for (int i = 0; i < 4; ++i) acc2[i] = (f32x4){0.f, 0.f, 0.f, 0.f};
        #pragma unroll
        for (int half = 0; half < 2; ++half) {
            short8 bfr[12];
            #pragma unroll
            for (int s = 0; s < 12; ++s) {
                const int ks = half * 12 + s;
                bfr[s] = (ks < 8)
                    ? *(const short8*)(&sROW[c * SROW_STRIDE + ks * 32 + 8 * g])
                    : *(const short8*)(&sRH[c * SRH_STRIDE + (ks - 8) * 32 + 8 * g]);
            }
            const short* wbase = Wc2T + (size_t)(w * 64 + c) * 768 + half * 384 + 8 * g;
            #pragma unroll
            for (int s = 0; s < 12; ++s) {
                #pragma unroll
                for (int ct = 0; ct < 4; ++ct) {
                    const short8 wf = *(const short8*)(wbase + (size_t)ct * 16 * 768 + 32 * s);
                    acc2[ct] = mfma_bf16(wf, bfr[s], acc2[ct]);
                }
            }
        }
        // epilogue B: hraw = (1-z)*hp + z*tanh(pre)
        {
            #pragma unroll
            for (int ct = 0; ct < 4; ++ct) {
                #pragma unroll
                for (int j = 0; j < 4; ++j) {
                    const int col = w * 64 + ct * 16 + 4 * g + j;
                    const float pre = acc2[ct][j] + sbh[col];
                    const float z = szb[col * 16 + c];
                    const float hp = bf2f(sROW[c * SROW_STRIDE + 256 + col]);
                    const float hr = (1.f - z) * hp + z * tanhf(pre);
                    shraw[c * SHR_STRIDE + col] = hr;
                }
            }
        }
        __syncthreads();

        // ---- column partial sums over own 16 rows -> coherent store ----
        {
            const int n = tid;
            float s1 = 0.f, s2 = 0.f;
            #pragma unroll
            for (int r = 0; r < 16; ++r) {
                const float v = shraw[r * SHR_STRIDE + n];
                s1 += v; s2 += v * v;
            }
            const int parC = t & 1;
            __hip_atomic_store(&Pst[((size_t)(parC * 2 + 0) * 16 + bid) * 512 + n], s1,
                               __ATOMIC_RELAXED, __HIP_MEMORY_SCOPE_AGENT);
            __hip_atomic_store(&Pst[((size_t)(parC * 2 + 1) * 16 + bid) * 512 + n], s2,
                               __ATOMIC_RELAXED, __HIP_MEMORY_SCOPE_AGENT);
        }
        // ---- fence-free device barrier ----
        __syncthreads();                 // all partial stores vmcnt-drained
        asm volatile("" ::: "memory");
        if (tid == 0)
            __hip_atomic_store(&flags[bid * 32], t + 1,
                               __ATOMIC_RELAXED, __HIP_MEMORY_SCOPE_AGENT);
        if (tid < 16) {
            while (__hip_atomic_load(&flags[tid * 32],
                                     __ATOMIC_RELAXED, __HIP_MEMORY_SCOPE_AGENT) < t + 1)
                __builtin_amdgcn_s_sleep(2);
        }
        __syncthreads();
    }

    // ---- tail: BN + outputs for t = Tt-1 ----
    {
        const int parP = (Tt - 1) & 1;
        const int n = tid;
        float s1 = 0.f, s2 = 0.f;
        #pragma unroll
        for (int j = 0; j < 16; ++j) {
            s1 += __hip_atomic_load(&Pst[((size_t)(parP * 2 + 0) * 16 + j) * 512 + n],
                                    __ATOMIC_RELAXED, __HIP_MEMORY_SCOPE_AGENT);
            s2 += __hip_atomic_load(&Pst[((size_t)(parP * 2 + 1) * 16 + j) * 512 + n],
                                    __ATOMIC_RELAXED, __HIP_MEMORY_SCOPE_AGENT);
        }
        const float mu = s1 * (1.f / 256.f);
        const float var = fmaxf(s2 * (1.f / 256.f) - mu * mu, 0.f);
        const float sc = bn_g[n] * rsqrtf(var + EPS_BN);
        scs[n] = sc; shs[n] = bn_b[n] - mu * sc;
        __syncthreads();
        #pragma unroll
        for (int rr = 0; rr < 2; ++rr) {
            const int r = 2 * w + rr;
            float p0 = 0.f, p1 = 0.f;
            #pragma unroll
            for (int i = 0; i < 8; ++i) {
                const int nn = lane + 64 * i;
                const float h = fmaf(shraw[r * SHR_STRIDE + nn], scs[nn], shs[nn]);
                out_hs[((size_t)(m0 + r) * Tt + (Tt - 1)) * Hh + nn] = h;
                p0 += h * sWhy[2 * nn]; p1 += h * sWhy[2 * nn + 1];
            }
            #pragma unroll
            for (int s = 1; s < 64; s <<= 1) { p0 += __shfl_xor(p0, s); p1 += __shfl_xor(p1, s); }
            if (lane == 0) {
                out_ys[((size_t)(m0 + r) * Tt + (Tt - 1)) * Oo + 0] = softplusf_(p0 + bhy0);
                out_ys[((size_t)(m0 + r) * Tt + (Tt - 1)) * Oo + 1] = softplusf_(p1 + bhy1);
            }
        }
    }
}

// ---------------------------------------------------------------------------
extern "C" void kernel_launch(void* const* d_in, const int* in_sizes, int n_in,
                              void* d_out, int out_size, void* d_ws, size_t ws_size,
                              hipStream_t stream)
{
    const float* input  = (const float*)d_in[0];
    const float* xmean  = (const float*)d_in[1];
    const float* W_dg_x = (const float*)d_in[2];
    const float* b_dg_x = (const float*)d_in[3];
    const float* W_dg_h = (const float*)d_in[4];
    const float* b_dg_h = (const float*)d_in[5];
    const float* W_xz   = (const float*)d_in[6];
    const float* W_hz   = (const float*)d_in[7];
    const float* W_mz   = (const float*)d_in[8];
    const float* b_z    = (const float*)d_in[9];
    const float* W_xr   = (const float*)d_in[10];
    const float* W_hr   = (const float*)d_in[11];
    const float* W_mr   = (const float*)d_in[12];
    const float* b_r    = (const float*)d_in[13];
    const float* W_xh   = (const float*)d_in[14];
    const float* W_hh   = (const float*)d_in[15];
    const float* W_mh   = (const float*)d_in[16];
    const float* b_h    = (const float*)d_in[17];
    const float* W_hy   = (const float*)d_in[18];
    const float* b_hy   = (const float*)d_in[19];
    const float* bn_g   = (const float*)d_in[20];
    const float* bn_b   = (const float*)d_in[21];

    float* out_ys = (float*)d_out;
    float* out_hs = out_ys + (size_t)Bb * Tt * Oo;

    char* p = (char*)d_ws;
    float* Xall = (float*)p;            p += (size_t)TBr * Ii * 4;
    short* Mall = (short*)p;            p += (size_t)TBr * Ii * 2;
    short* Dall = (short*)p;            p += (size_t)TBr * Ii * 2;
    short* Gxb  = (short*)p;            p += (size_t)TBr * Ii * 2;
    short* Ghb  = (short*)p;            p += (size_t)TBr * Hh * 2;
    short* Xe   = (short*)p;            p += (size_t)TBr * Ii * 2;
    short* Wc1T = (short*)p;            p += (size_t)1024 * 768 * 2;
    short* Wc2T = (short*)p;            p += (size_t)512 * 768 * 2;
    short* WdgxT= (short*)p;            p += (size_t)128 * 128 * 2;
    short* WdghT= (short*)p;            p += (size_t)512 * 128 * 2;
    float* bias1= (float*)p;            p += 1024 * 4;
    float* Pst  = (float*)p;            p += (size_t)2 * 2 * 16 * 512 * 4;
    int*   flags= (int*)p;              p += 16 * 32 * 4;

    hipMemsetAsync(flags, 0, 16 * 32 * 4, stream);

    repack_kernel<<<dim3(Tt / 32, Ii / 32, Bb * 3), dim3(32, 32), 0, stream>>>(input, Xall, Mall, Dall);

    {
        const int total = 1024 * 768 + 512 * 768 + 128 * 128 + 512 * 128 + 1024;
        pack_weights_kernel<<<(total + 255) / 256, 256, 0, stream>>>(
            W_dg_x, W_dg_h,
            W_xz, W_hz, W_mz, b_z,
            W_xr, W_hr, W_mr, b_r,
            W_xh, W_hh, W_mh,
            Wc1T, Wc2T, WdgxT, WdghT, bias1);
    }

    gdecay_kernel<<<dim3(TBr / 32, Ii / 64), 64, 0, stream>>>(Dall, WdgxT, b_dg_x, Gxb, Ii);
    gdecay_kernel<<<dim3(TBr / 32, Hh / 64), 64, 0, stream>>>(Dall, WdghT, b_dg_h, Ghb, Hh);

    xeff_scan_kernel<<<(Bb * Ii) / 256, 256, 0, stream>>>(Xall, Mall, Gxb, xmean, Xe);

    grud_persistent<<<16, 512, 0, stream>>>(
        Xe, Mall, Ghb, Wc1T, Wc2T, bias1, b_h, bn_g, bn_b,
        W_hy, b_hy, Pst, flags, out_hs, out_ys);
}

// Round 6
// 3427.505 us; speedup vs baseline: 8.2301x; 8.2301x over previous
//
#include <hip/hip_runtime.h>
#include <math.h>

#define Bb 256
#define Ii 128
#define Tt 256
#define Hh 512
#define Oo 2
#define TBr (Tt*Bb)
#define EPS_BN 1e-5f

typedef __attribute__((ext_vector_type(8))) short short8;
typedef __attribute__((ext_vector_type(8))) __bf16 bf16x8;
typedef __attribute__((ext_vector_type(4))) float f32x4;
typedef unsigned long long u64;

__device__ __forceinline__ f32x4 mfma_bf16(short8 a, short8 b, f32x4 c) {
    return __builtin_amdgcn_mfma_f32_16x16x32_bf16(
        __builtin_bit_cast(bf16x8, a), __builtin_bit_cast(bf16x8, b), c, 0, 0, 0);
}
__device__ __forceinline__ short f2bf(float f) {
    union { float f; unsigned u; } v; v.f = f;
    unsigned r = (v.u + 0x7FFFu + ((v.u >> 16) & 1u)) >> 16;
    return (short)r;
}
__device__ __forceinline__ float bf2f(short s) {
    union { unsigned u; float f; } v; v.u = ((unsigned)(unsigned short)s) << 16;
    return v.f;
}
__device__ __forceinline__ float sigmoidf_(float x) { return 1.f / (1.f + expf(-x)); }
__device__ __forceinline__ float softplusf_(float x) { return fmaxf(x, 0.f) + log1pf(expf(-fabsf(x))); }

#define ALD_F(p)  __hip_atomic_load((p),  __ATOMIC_RELAXED, __HIP_MEMORY_SCOPE_AGENT)
#define AST_F(p,v) __hip_atomic_store((p), (v), __ATOMIC_RELAXED, __HIP_MEMORY_SCOPE_AGENT)

// ---------------------------------------------------------------------------
// repack: input [B,3,I,T] fp32 -> time-major X fp32 [T,B,I], M bf16, D bf16
// ---------------------------------------------------------------------------
__global__ __launch_bounds__(1024) void repack_kernel(const float* __restrict__ in,
                                                      float* __restrict__ Xall,
                                                      short* __restrict__ Mall,
                                                      short* __restrict__ Dall)
{
    __shared__ float tile[32][33];
    const int bz = blockIdx.z;
    const int b = bz / 3, cch = bz % 3;
    const int t0 = blockIdx.x * 32, i0 = blockIdx.y * 32;
    const int tx = threadIdx.x, ty = threadIdx.y;
    const float* src = in + ((size_t)b * 3 + cch) * (size_t)Ii * Tt;
    tile[ty][tx] = src[(size_t)(i0 + ty) * Tt + t0 + tx];
    __syncthreads();
    const float v = tile[tx][ty];
    const size_t off = ((size_t)(t0 + ty) * Bb + b) * Ii + i0 + tx;
    if (cch == 0)      Xall[off] = v;
    else if (cch == 1) Mall[off] = f2bf(v);
    else               Dall[off] = f2bf(v);
}

// ---------------------------------------------------------------------------
// pack weights -> bf16 transposed (n-major, k rows) for MFMA fragments
// ---------------------------------------------------------------------------
__global__ __launch_bounds__(256) void pack_weights_kernel(
    const float* __restrict__ W_dg_x, const float* __restrict__ W_dg_h,
    const float* __restrict__ W_xz, const float* __restrict__ W_hz, const float* __restrict__ W_mz, const float* __restrict__ b_z,
    const float* __restrict__ W_xr, const float* __restrict__ W_hr, const float* __restrict__ W_mr, const float* __restrict__ b_r,
    const float* __restrict__ W_xh, const float* __restrict__ W_hh, const float* __restrict__ W_mh,
    short* __restrict__ Wc1T, short* __restrict__ Wc2T,
    short* __restrict__ WdgxT, short* __restrict__ WdghT, float* __restrict__ bias1)
{
    const int idx = blockIdx.x * blockDim.x + threadIdx.x;
    const int n1 = 1024 * 768, n2 = 512 * 768, n3 = 128 * 128, n4 = 512 * 128;
    if (idx < n1) {
        const int n = idx / 768, k = idx % 768;
        const int col = (n < Hh) ? n : (n - Hh);
        const float* Wx = (n < Hh) ? W_xz : W_xr;
        const float* Wm = (n < Hh) ? W_mz : W_mr;
        const float* Wh = (n < Hh) ? W_hz : W_hr;
        float v;
        if (k < Ii)        v = Wx[(size_t)k * Hh + col];
        else if (k < 2*Ii) v = Wm[(size_t)(k - Ii) * Hh + col];
        else               v = Wh[(size_t)(k - 2*Ii) * Hh + col];
        Wc1T[idx] = f2bf(v);
    } else if (idx < n1 + n2) {
        const int j = idx - n1;
        const int n = j / 768, k = j % 768;
        float v;
        if (k < Ii)        v = W_xh[(size_t)k * Hh + n];
        else if (k < 2*Ii) v = W_mh[(size_t)(k - Ii) * Hh + n];
        else               v = W_hh[(size_t)(k - 2*Ii) * Hh + n];
        Wc2T[j] = f2bf(v);
    } else if (idx < n1 + n2 + n3) {
        const int j = idx - n1 - n2;
        const int n = j >> 7, k = j & 127;
        WdgxT[j] = f2bf(W_dg_x[(size_t)k * Ii + n]);
    } else if (idx < n1 + n2 + n3 + n4) {
        const int j = idx - n1 - n2 - n3;
        const int n = j >> 7, k = j & 127;
        WdghT[j] = f2bf(W_dg_h[(size_t)k * Hh + n]);
    } else if (idx < n1 + n2 + n3 + n4 + 1024) {
        const int n = idx - n1 - n2 - n3 - n4;
        bias1[n] = (n < Hh) ? b_z[n] : b_r[n - Hh];
    }
}

// ---------------------------------------------------------------------------
// gdecay: C = bf16(exp(-relu(A @ B + bias)))
// ---------------------------------------------------------------------------
__global__ __launch_bounds__(64) void gdecay_kernel(const short* __restrict__ A,
                                                    const short* __restrict__ BT,
                                                    const float* __restrict__ bias,
                                                    short* __restrict__ C, int N)
{
    const int lane = threadIdx.x;
    const int c = lane & 15, g = lane >> 4;
    const int m0 = blockIdx.x * 32, n0 = blockIdx.y * 64;
    const short* a0 = A + (size_t)(m0 + c) * Ii + 8 * g;
    const short* a1 = a0 + (size_t)16 * Ii;
    const short* bw = BT + (size_t)(n0 + c) * Ii + 8 * g;
    f32x4 acc[2][4];
    #pragma unroll
    for (int i = 0; i < 2; ++i)
        #pragma unroll
        for (int f = 0; f < 4; ++f) acc[i][f] = (f32x4){0.f, 0.f, 0.f, 0.f};
    #pragma unroll
    for (int k0 = 0; k0 < 128; k0 += 32) {
        const short8 av0 = *(const short8*)(a0 + k0);
        const short8 av1 = *(const short8*)(a1 + k0);
        #pragma unroll
        for (int fn = 0; fn < 4; ++fn) {
            const short8 bv = *(const short8*)(bw + (size_t)fn * 16 * Ii + k0);
            acc[0][fn] = mfma_bf16(av0, bv, acc[0][fn]);
            acc[1][fn] = mfma_bf16(av1, bv, acc[1][fn]);
        }
    }
    #pragma unroll
    for (int fn = 0; fn < 4; ++fn) {
        const int n = n0 + fn * 16 + c;
        const float bs = bias[n];
        #pragma unroll
        for (int fm = 0; fm < 2; ++fm) {
            #pragma unroll
            for (int j = 0; j < 4; ++j) {
                const int m = m0 + fm * 16 + 4 * g + j;
                const float v = expf(-fmaxf(acc[fm][fn][j] + bs, 0.f));
                C[(size_t)m * N + n] = f2bf(v);
            }
        }
    }
}

// ---------------------------------------------------------------------------
// x_last scan + x_eff -> Xe bf16 [T,B,I]
// ---------------------------------------------------------------------------
__global__ __launch_bounds__(256) void xeff_scan_kernel(const float* __restrict__ Xall,
                                                        const short* __restrict__ Mall,
                                                        const short* __restrict__ Gx,
                                                        const float* __restrict__ xmean_p,
                                                        short* __restrict__ Xe)
{
    const int bi = blockIdx.x * blockDim.x + threadIdx.x;
    if (bi >= Bb * Ii) return;
    const float xm = xmean_p[0];
    float xl = 0.f;
    for (int t = 0; t < Tt; ++t) {
        const size_t off = (size_t)t * Bb * Ii + bi;
        const float x = Xall[off];
        const float m = bf2f(Mall[off]);
        const float gx = bf2f(Gx[off]);
        if (m > 0.f) xl = x;
        Xe[off] = f2bf(m * x + (1.f - m) * (gx * xl + (1.f - gx) * xm));
    }
}

// ---------------------------------------------------------------------------
// persistent: 256 blocks x 512 thr. block (mt = bid&15, ng = bid>>4):
// rows m0=mt*16..+16, cols ng*32 (z), 512+ng*32 (r), ng*32 (htilde).
// Weights in VGPRs. Cross-block data via relaxed AGENT atomics (IC-coherent,
// never touches L2 coherence). 3 fence-free flag barriers per step.
// ---------------------------------------------------------------------------
#define XM_STR 264
#define HP_STR 520
#define RH_STR 520
#define HR_STR 33

__global__ __launch_bounds__(512, 1) void grud_persistent(
    const short* __restrict__ Xe, const short* __restrict__ Ma,
    const short* __restrict__ Ghb,
    const short* __restrict__ Wc1T, const short* __restrict__ Wc2T,
    const float* __restrict__ bias1, const float* __restrict__ b_h,
    const float* __restrict__ bn_g, const float* __restrict__ bn_b,
    const float* __restrict__ Why, const float* __restrict__ bhy,
    short* __restrict__ hpG,          // [256][512] bf16  (atomic-only)
    short* __restrict__ rhG,          // [256][512] bf16  (atomic-only)
    float* __restrict__ Pst,          // [2][16][512] f32 (atomic-only)
    int* __restrict__ flags,          // [256][16] int    (atomic-only)
    float* __restrict__ out_hs, float* __restrict__ out_ys)
{
    const int bid = blockIdx.x, tid = threadIdx.x;
    const int w = tid >> 6, lane = tid & 63, c = lane & 15, g = lane >> 4;
    const int mt = bid & 15, ng = bid >> 4;
    const int m0 = mt * 16;

    __shared__ short sXM[16 * XM_STR];       // 8.25 KB
    __shared__ short sHP[16 * HP_STR];       // 16.25 KB
    __shared__ short sRH[16 * RH_STR];       // 16.25 KB
    __shared__ float sZ[32 * 17];            // 2.1 KB   [localcol][row]
    __shared__ float sHR[16 * HR_STR];       // 2.1 KB   [row][localcol]
    __shared__ float scratch[1536];          // 6 KB k-split reduce
    __shared__ float sWhy[1024];             // 4 KB
    __shared__ float scs[32], shs[32];
    __shared__ float ysred[16];

    // ---- constant staging + weight preload (once) ----
    sWhy[tid] = Why[tid]; sWhy[tid + 512] = Why[tid + 512];
    const float bhy0 = bhy[0], bhy1 = bhy[1];

    const int colt = w & 3, kh = w >> 2;             // phase A role
    const int colbaseA = (colt < 2) ? (ng * 32 + colt * 16)
                                    : (512 + ng * 32 + (colt - 2) * 16);
    short8 wA[12];
    {
        const short* bw = Wc1T + (size_t)(colbaseA + c) * 768 + kh * 384 + 8 * g;
        #pragma unroll
        for (int s = 0; s < 12; ++s) wA[s] = *(const short8*)(bw + 32 * s);
    }
    const int colt2 = w & 1, kq = w >> 1;            // phase B role
    const int colbaseB = ng * 32 + colt2 * 16;
    short8 wB[6];
    {
        const short* bw = Wc2T + (size_t)(colbaseB + c) * 768 + kq * 192 + 8 * g;
        #pragma unroll
        for (int s = 0; s < 6; ++s) wB[s] = *(const short8*)(bw + 32 * s);
    }
    __syncthreads();

    int ep = 0;
    for (int t = 0; t < Tt; ++t) {
        // ---- stage [Xe|Ma] ----
        {
            const int r = tid >> 5, cu = tid & 31;
            const short* src = (cu < 16)
                ? (Xe + ((size_t)t * Bb + m0 + r) * Ii + 8 * cu)
                : (Ma + ((size_t)t * Bb + m0 + r) * Ii + 8 * (cu - 16));
            *(short8*)(&sXM[r * XM_STR + 8 * cu]) = *(const short8*)src;
        }
        // ---- stage hp panel (atomic: written by peers' phase C) ----
        if (t > 0) {
            #pragma unroll
            for (int i = 0; i < 4; ++i) {
                const int e = tid + i * 512;
                const int r = e >> 7, cu = e & 127;
                const u64 v = ALD_F((const u64*)(hpG + ((size_t)(m0 + r) * Hh + 4 * cu)));
                *(u64*)(&sHP[r * HP_STR + 4 * cu]) = v;
            }
        } else {
            #pragma unroll
            for (int i = 0; i < 4; ++i) {
                const int e = tid + i * 512;
                const int r = e >> 7, cu = e & 127;
                *(u64*)(&sHP[r * HP_STR + 4 * cu]) = 0ull;
            }
        }
        // ---- ys(t-1): row bid, reading out_hs written by phase C(t-1) ----
        if (t > 0) {
            const float h = ALD_F(&out_hs[((size_t)bid * Tt + (t - 1)) * Hh + tid]);
            float p0 = h * sWhy[2 * tid], p1 = h * sWhy[2 * tid + 1];
            #pragma unroll
            for (int s = 1; s < 64; s <<= 1) { p0 += __shfl_xor(p0, s); p1 += __shfl_xor(p1, s); }
            if (lane == 0) { ysred[w * 2] = p0; ysred[w * 2 + 1] = p1; }
        }
        __syncthreads();
        if (t > 0 && tid == 0) {
            float q0 = 0.f, q1 = 0.f;
            #pragma unroll
            for (int i = 0; i < 8; ++i) { q0 += ysred[2 * i]; q1 += ysred[2 * i + 1]; }
            out_ys[((size_t)bid * Tt + (t - 1)) * Oo + 0] = softplusf_(q0 + bhy0);
            out_ys[((size_t)bid * Tt + (t - 1)) * Oo + 1] = softplusf_(q1 + bhy1);
        }

        // ================= Phase A: [Xe|Ma|hp] @ Wc1 (z,r cols) ============
        {
            f32x4 acc = (f32x4){0.f, 0.f, 0.f, 0.f};
            #pragma unroll
            for (int s = 0; s < 12; ++s) {
                const int k = kh * 384 + 32 * s;
                const short8 frag = (k < 256)
                    ? *(const short8*)(&sXM[c * XM_STR + k + 8 * g])
                    : *(const short8*)(&sHP[c * HP_STR + (k - 256) + 8 * g]);
                acc = mfma_bf16(wA[s], frag, acc);
            }
            if (kh == 1) {
                float* sp = scratch + (colt * 64 + lane) * 4;
                sp[0] = acc[0]; sp[1] = acc[1]; sp[2] = acc[2]; sp[3] = acc[3];
            }
            __syncthreads();
            if (kh == 0) {
                const float* sp = scratch + (colt * 64 + lane) * 4;
                acc[0] += sp[0]; acc[1] += sp[1]; acc[2] += sp[2]; acc[3] += sp[3];
                if (colt < 2) {
                    #pragma unroll
                    for (int j = 0; j < 4; ++j) {
                        const int lc = colt * 16 + 4 * g + j;
                        const float v = sigmoidf_(acc[j] + bias1[ng * 32 + lc]);
                        sZ[lc * 17 + c] = v;
                    }
                } else {
                    const int nn0 = ng * 32 + (colt - 2) * 16 + 4 * g;
                    short rh[4];
                    #pragma unroll
                    for (int j = 0; j < 4; ++j) {
                        const float v = sigmoidf_(acc[j] + bias1[512 + nn0 + j]);
                        rh[j] = f2bf(v * bf2f(sHP[c * HP_STR + nn0 + j]));
                    }
                    AST_F((u64*)(rhG + ((size_t)(m0 + c) * Hh + nn0)), *(const u64*)rh);
                }
            }
        }
        // ---- barrier 1 ----
        ep += 1;
        __syncthreads();
        if (tid == 0) AST_F(&flags[bid * 16], ep);
        if (tid < 256) {
            while (__hip_atomic_load(&flags[tid * 16], __ATOMIC_RELAXED, __HIP_MEMORY_SCOPE_AGENT) < ep)
                __builtin_amdgcn_s_sleep(1);
        }
        __syncthreads();

        // ---- stage RH panel (atomic) ----
        #pragma unroll
        for (int i = 0; i < 4; ++i) {
            const int e = tid + i * 512;
            const int r = e >> 7, cu = e & 127;
            const u64 v = ALD_F((const u64*)(rhG + ((size_t)(m0 + r) * Hh + 4 * cu)));
            *(u64*)(&sRH[r * RH_STR + 4 * cu]) = v;
        }
        __syncthreads();

        // ================= Phase B: [Xe|Ma|RH] @ Wc2 (htilde cols) =========
        {
            f32x4 acc2 = (f32x4){0.f, 0.f, 0.f, 0.f};
            #pragma unroll
            for (int s = 0; s < 6; ++s) {
                const int k = kq * 192 + 32 * s;
                const short8 frag = (k < 256)
                    ? *(const short8*)(&sXM[c * XM_STR + k + 8 * g])
                    : *(const short8*)(&sRH[c * RH_STR + (k - 256) + 8 * g]);
                acc2 = mfma_bf16(wB[s], frag, acc2);
            }
            if (kq > 0) {
                float* sp = scratch + ((colt2 * 3 + kq - 1) * 64 + lane) * 4;
                sp[0] = acc2[0]; sp[1] = acc2[1]; sp[2] = acc2[2]; sp[3] = acc2[3];
            }
            __syncthreads();
            if (kq == 0) {
                #pragma unroll
                for (int qq = 0; qq < 3; ++qq) {
                    const float* sp = scratch + ((colt2 * 3 + qq) * 64 + lane) * 4;
                    acc2[0] += sp[0]; acc2[1] += sp[1]; acc2[2] += sp[2]; acc2[3] += sp[3];
                }
                #pragma unroll
                for (int j = 0; j < 4; ++j) {
                    const int lc = colt2 * 16 + 4 * g + j;
                    const int col = ng * 32 + lc;
                    const float pre = acc2[j] + b_h[col];
                    const float z = sZ[lc * 17 + c];
                    const float hp = bf2f(sHP[c * HP_STR + col]);
                    const float hr = (1.f - z) * hp + z * tanhf(pre);
                    sHR[c * HR_STR + lc] = hr;
                    float sp_ = hr, sq_ = hr * hr;
                    sp_ += __shfl_xor(sp_, 1); sq_ += __shfl_xor(sq_, 1);
                    sp_ += __shfl_xor(sp_, 2); sq_ += __shfl_xor(sq_, 2);
                    sp_ += __shfl_xor(sp_, 4); sq_ += __shfl_xor(sq_, 4);
                    sp_ += __shfl_xor(sp_, 8); sq_ += __shfl_xor(sq_, 8);
                    if (c == 0) {
                        AST_F(&Pst[(size_t)mt * 512 + col], sp_);
                        AST_F(&Pst[(size_t)(16 + mt) * 512 + col], sq_);
                    }
                }
            }
        }
        // ---- barrier 2 ----
        ep += 1;
        __syncthreads();
        if (tid == 0) AST_F(&flags[bid * 16], ep);
        if (tid < 256) {
            while (__hip_atomic_load(&flags[tid * 16], __ATOMIC_RELAXED, __HIP_MEMORY_SCOPE_AGENT) < ep)
                __builtin_amdgcn_s_sleep(1);
        }
        __syncthreads();

        // ================= Phase C: BN stats + outputs + hp(t+1) ===========
        {
            const int lc = tid >> 4, jm = tid & 15;   // lc<32, jm<16
            const int col = ng * 32 + lc;
            float s1 = ALD_F(&Pst[(size_t)jm * 512 + col]);
            float s2 = ALD_F(&Pst[(size_t)(16 + jm) * 512 + col]);
            s1 += __shfl_xor(s1, 1); s2 += __shfl_xor(s2, 1);
            s1 += __shfl_xor(s1, 2); s2 += __shfl_xor(s2, 2);
            s1 += __shfl_xor(s1, 4); s2 += __shfl_xor(s2, 4);
            s1 += __shfl_xor(s1, 8); s2 += __shfl_xor(s2, 8);
            if (jm == 0) {
                const float mu = s1 * (1.f / 256.f);
                const float var = fmaxf(s2 * (1.f / 256.f) - mu * mu, 0.f);
                const float sc = bn_g[col] * rsqrtf(var + EPS_BN);
                scs[lc] = sc; shs[lc] = bn_b[col] - mu * sc;
            }
        }
        __syncthreads();
        if (tid < 256) {
            const int r = tid >> 4, lp = tid & 15;
            const int lc0 = 2 * lp;
            const int col0 = ng * 32 + lc0;
            const float h0 = fmaf(sHR[r * HR_STR + lc0],     scs[lc0],     shs[lc0]);
            const float h1 = fmaf(sHR[r * HR_STR + lc0 + 1], scs[lc0 + 1], shs[lc0 + 1]);
            float hv[2] = {h0, h1};
            AST_F((u64*)(&out_hs[((size_t)(m0 + r) * Tt + t) * Hh + col0]), *(const u64*)hv);
            if (t + 1 < Tt) {
                const unsigned gv = *(const unsigned*)(Ghb + ((size_t)(t + 1) * Bb + m0 + r) * Hh + col0);
                const unsigned pk = (unsigned)(unsigned short)f2bf(h0 * bf2f((short)(gv & 0xffffu)))
                                  | ((unsigned)(unsigned short)f2bf(h1 * bf2f((short)(gv >> 16))) << 16);
                AST_F((unsigned*)(hpG + ((size_t)(m0 + r) * Hh + col0)), pk);
            }
        }
        // ---- barrier 3 ----
        ep += 1;
        __syncthreads();
        if (tid == 0) AST_F(&flags[bid * 16], ep);
        if (tid < 256) {
            while (__hip_atomic_load(&flags[tid * 16], __ATOMIC_RELAXED, __HIP_MEMORY_SCOPE_AGENT) < ep)
                __builtin_amdgcn_s_sleep(1);
        }
        __syncthreads();
    }

    // ---- tail: ys for t = Tt-1 ----
    {
        const float h = ALD_F(&out_hs[((size_t)bid * Tt + (Tt - 1)) * Hh + tid]);
        float p0 = h * sWhy[2 * tid], p1 = h * sWhy[2 * tid + 1];
        #pragma unroll
        for (int s = 1; s < 64; s <<= 1) { p0 += __shfl_xor(p0, s); p1 += __shfl_xor(p1, s); }
        if (lane == 0) { ysred[w * 2] = p0; ysred[w * 2 + 1] = p1; }
        __syncthreads();
        if (tid == 0) {
            float q0 = 0.f, q1 = 0.f;
            #pragma unroll
            for (int i = 0; i < 8; ++i) { q0 += ysred[2 * i]; q1 += ysred[2 * i + 1]; }
            out_ys[((size_t)bid * Tt + (Tt - 1)) * Oo + 0] = softplusf_(q0 + bhy0);
            out_ys[((size_t)bid * Tt + (Tt - 1)) * Oo + 1] = softplusf_(q1 + bhy1);
        }
    }
}

// ---------------------------------------------------------------------------
extern "C" void kernel_launch(void* const* d_in, const int* in_sizes, int n_in,
                              void* d_out, int out_size, void* d_ws, size_t ws_size,
                              hipStream_t stream)
{
    const float* input  = (const float*)d_in[0];
    const float* xmean  = (const float*)d_in[1];
    const float* W_dg_x = (const float*)d_in[2];
    const float* b_dg_x = (const float*)d_in[3];
    const float* W_dg_h = (const float*)d_in[4];
    const float* b_dg_h = (const float*)d_in[5];
    const float* W_xz   = (const float*)d_in[6];
    const float* W_hz   = (const float*)d_in[7];
    const float* W_mz   = (const float*)d_in[8];
    const float* b_z    = (const float*)d_in[9];
    const float* W_xr   = (const float*)d_in[10];
    const float* W_hr   = (const float*)d_in[11];
    const float* W_mr   = (const float*)d_in[12];
    const float* b_r    = (const float*)d_in[13];
    const float* W_xh   = (const float*)d_in[14];
    const float* W_hh   = (const float*)d_in[15];
    const float* W_mh   = (const float*)d_in[16];
    const float* b_h    = (const float*)d_in[17];
    const float* W_hy   = (const float*)d_in[18];
    const float* b_hy   = (const float*)d_in[19];
    const float* bn_g   = (const float*)d_in[20];
    const float* bn_b   = (const float*)d_in[21];

    float* out_ys = (float*)d_out;
    float* out_hs = out_ys + (size_t)Bb * Tt * Oo;

    char* p = (char*)d_ws;
    float* Xall = (float*)p;            p += (size_t)TBr * Ii * 4;
    short* Mall = (short*)p;            p += (size_t)TBr * Ii * 2;
    short* Dall = (short*)p;            p += (size_t)TBr * Ii * 2;
    short* Gxb  = (short*)p;            p += (size_t)TBr * Ii * 2;
    short* Ghb  = (short*)p;            p += (size_t)TBr * Hh * 2;
    short* Xe   = (short*)p;            p += (size_t)TBr * Ii * 2;
    short* Wc1T = (short*)p;            p += (size_t)1024 * 768 * 2;
    short* Wc2T = (short*)p;            p += (size_t)512 * 768 * 2;
    short* WdgxT= (short*)p;            p += (size_t)128 * 128 * 2;
    short* WdghT= (short*)p;            p += (size_t)512 * 128 * 2;
    float* bias1= (float*)p;            p += 1024 * 4;
    short* hpG  = (short*)p;            p += (size_t)Bb * Hh * 2;
    short* rhG  = (short*)p;            p += (size_t)Bb * Hh * 2;
    float* Pst  = (float*)p;            p += (size_t)2 * 16 * 512 * 4;
    int*   flags= (int*)p;              p += 256 * 16 * 4;

    hipMemsetAsync(flags, 0, 256 * 16 * 4, stream);

    repack_kernel<<<dim3(Tt / 32, Ii / 32, Bb * 3), dim3(32, 32), 0, stream>>>(input, Xall, Mall, Dall);

    {
        const int total = 1024 * 768 + 512 * 768 + 128 * 128 + 512 * 128 + 1024;
        pack_weights_kernel<<<(total + 255) / 256, 256, 0, stream>>>(
            W_dg_x, W_dg_h,
            W_xz, W_hz, W_mz, b_z,
            W_xr, W_hr, W_mr, b_r,
            W_xh, W_hh, W_mh,
            Wc1T, Wc2T, WdgxT, WdghT, bias1);
    }

    gdecay_kernel<<<dim3(TBr / 32, Ii / 64), 64, 0, stream>>>(Dall, WdgxT, b_dg_x, Gxb, Ii);
    gdecay_kernel<<<dim3(TBr / 32, Hh / 64), 64, 0, stream>>>(Dall, WdghT, b_dg_h, Ghb, Hh);

    xeff_scan_kernel<<<(Bb * Ii) / 256, 256, 0, stream>>>(Xall, Mall, Gxb, xmean, Xe);

    grud_persistent<<<256, 512, 0, stream>>>(
        Xe, Mall, Ghb, Wc1T, Wc2T, bias1, b_h, bn_g, bn_b,
        W_hy, b_hy, hpG, rhG, Pst, flags, out_hs, out_ys);
}

// Round 7
// 2728.370 us; speedup vs baseline: 10.3391x; 1.2562x over previous
//
#include <hip/hip_runtime.h>
#include <math.h>

#define Bb 256
#define Ii 128
#define Tt 256
#define Hh 512
#define Oo 2
#define TBr (Tt*Bb)
#define EPS_BN 1e-5f

typedef __attribute__((ext_vector_type(8))) short short8;
typedef __attribute__((ext_vector_type(8))) __bf16 bf16x8;
typedef __attribute__((ext_vector_type(4))) float f32x4;
typedef __attribute__((ext_vector_type(2))) float f32x2;
typedef unsigned long long u64;

__device__ __forceinline__ f32x4 mfma_bf16(short8 a, short8 b, f32x4 c) {
    return __builtin_amdgcn_mfma_f32_16x16x32_bf16(
        __builtin_bit_cast(bf16x8, a), __builtin_bit_cast(bf16x8, b), c, 0, 0, 0);
}
__device__ __forceinline__ short f2bf(float f) {
    union { float f; unsigned u; } v; v.f = f;
    unsigned r = (v.u + 0x7FFFu + ((v.u >> 16) & 1u)) >> 16;
    return (short)r;
}
__device__ __forceinline__ float bf2f(short s) {
    union { unsigned u; float f; } v; v.u = ((unsigned)(unsigned short)s) << 16;
    return v.f;
}
__device__ __forceinline__ float sigmoidf_(float x) { return 1.f / (1.f + expf(-x)); }
__device__ __forceinline__ float softplusf_(float x) { return fmaxf(x, 0.f) + log1pf(expf(-fabsf(x))); }

#define ALD_F(p)  __hip_atomic_load((p),  __ATOMIC_RELAXED, __HIP_MEMORY_SCOPE_AGENT)
#define AST_F(p,v) __hip_atomic_store((p), (v), __ATOMIC_RELAXED, __HIP_MEMORY_SCOPE_AGENT)
#define AADD_F(p,v) (void)__hip_atomic_fetch_add((p), (v), __ATOMIC_RELAXED, __HIP_MEMORY_SCOPE_AGENT)

// ---------------------------------------------------------------------------
// repack: input [B,3,I,T] fp32 -> time-major X fp32 [T,B,I], M bf16, D bf16
// ---------------------------------------------------------------------------
__global__ __launch_bounds__(1024) void repack_kernel(const float* __restrict__ in,
                                                      float* __restrict__ Xall,
                                                      short* __restrict__ Mall,
                                                      short* __restrict__ Dall)
{
    __shared__ float tile[32][33];
    const int bz = blockIdx.z;
    const int b = bz / 3, cch = bz % 3;
    const int t0 = blockIdx.x * 32, i0 = blockIdx.y * 32;
    const int tx = threadIdx.x, ty = threadIdx.y;
    const float* src = in + ((size_t)b * 3 + cch) * (size_t)Ii * Tt;
    tile[ty][tx] = src[(size_t)(i0 + ty) * Tt + t0 + tx];
    __syncthreads();
    const float v = tile[tx][ty];
    const size_t off = ((size_t)(t0 + ty) * Bb + b) * Ii + i0 + tx;
    if (cch == 0)      Xall[off] = v;
    else if (cch == 1) Mall[off] = f2bf(v);
    else               Dall[off] = f2bf(v);
}

// ---------------------------------------------------------------------------
// pack weights -> bf16 transposed (n-major, k rows) for MFMA fragments
// ---------------------------------------------------------------------------
__global__ __launch_bounds__(256) void pack_weights_kernel(
    const float* __restrict__ W_dg_x, const float* __restrict__ W_dg_h,
    const float* __restrict__ W_xz, const float* __restrict__ W_hz, const float* __restrict__ W_mz, const float* __restrict__ b_z,
    const float* __restrict__ W_xr, const float* __restrict__ W_hr, const float* __restrict__ W_mr, const float* __restrict__ b_r,
    const float* __restrict__ W_xh, const float* __restrict__ W_hh, const float* __restrict__ W_mh,
    short* __restrict__ Wc1T, short* __restrict__ Wc2T,
    short* __restrict__ WdgxT, short* __restrict__ WdghT, float* __restrict__ bias1)
{
    const int idx = blockIdx.x * blockDim.x + threadIdx.x;
    const int n1 = 1024 * 768, n2 = 512 * 768, n3 = 128 * 128, n4 = 512 * 128;
    if (idx < n1) {
        const int n = idx / 768, k = idx % 768;
        const int col = (n < Hh) ? n : (n - Hh);
        const float* Wx = (n < Hh) ? W_xz : W_xr;
        const float* Wm = (n < Hh) ? W_mz : W_mr;
        const float* Wh = (n < Hh) ? W_hz : W_hr;
        float v;
        if (k < Ii)        v = Wx[(size_t)k * Hh + col];
        else if (k < 2*Ii) v = Wm[(size_t)(k - Ii) * Hh + col];
        else               v = Wh[(size_t)(k - 2*Ii) * Hh + col];
        Wc1T[idx] = f2bf(v);
    } else if (idx < n1 + n2) {
        const int j = idx - n1;
        const int n = j / 768, k = j % 768;
        float v;
        if (k < Ii)        v = W_xh[(size_t)k * Hh + n];
        else if (k < 2*Ii) v = W_mh[(size_t)(k - Ii) * Hh + n];
        else               v = W_hh[(size_t)(k - 2*Ii) * Hh + n];
        Wc2T[j] = f2bf(v);
    } else if (idx < n1 + n2 + n3) {
        const int j = idx - n1 - n2;
        const int n = j >> 7, k = j & 127;
        WdgxT[j] = f2bf(W_dg_x[(size_t)k * Ii + n]);
    } else if (idx < n1 + n2 + n3 + n4) {
        const int j = idx - n1 - n2 - n3;
        const int n = j >> 7, k = j & 127;
        WdghT[j] = f2bf(W_dg_h[(size_t)k * Hh + n]);
    } else if (idx < n1 + n2 + n3 + n4 + 1024) {
        const int n = idx - n1 - n2 - n3 - n4;
        bias1[n] = (n < Hh) ? b_z[n] : b_r[n - Hh];
    }
}

// ---------------------------------------------------------------------------
// gdecay: C = bf16(exp(-relu(A @ B + bias)))
// ---------------------------------------------------------------------------
__global__ __launch_bounds__(64) void gdecay_kernel(const short* __restrict__ A,
                                                    const short* __restrict__ BT,
                                                    const float* __restrict__ bias,
                                                    short* __restrict__ C, int N)
{
    const int lane = threadIdx.x;
    const int c = lane & 15, g = lane >> 4;
    const int m0 = blockIdx.x * 32, n0 = blockIdx.y * 64;
    const short* a0 = A + (size_t)(m0 + c) * Ii + 8 * g;
    const short* a1 = a0 + (size_t)16 * Ii;
    const short* bw = BT + (size_t)(n0 + c) * Ii + 8 * g;
    f32x4 acc[2][4];
    #pragma unroll
    for (int i = 0; i < 2; ++i)
        #pragma unroll
        for (int f = 0; f < 4; ++f) acc[i][f] = (f32x4){0.f, 0.f, 0.f, 0.f};
    #pragma unroll
    for (int k0 = 0; k0 < 128; k0 += 32) {
        const short8 av0 = *(const short8*)(a0 + k0);
        const short8 av1 = *(const short8*)(a1 + k0);
        #pragma unroll
        for (int fn = 0; fn < 4; ++fn) {
            const short8 bv = *(const short8*)(bw + (size_t)fn * 16 * Ii + k0);
            acc[0][fn] = mfma_bf16(av0, bv, acc[0][fn]);
            acc[1][fn] = mfma_bf16(av1, bv, acc[1][fn]);
        }
    }
    #pragma unroll
    for (int fn = 0; fn < 4; ++fn) {
        const int n = n0 + fn * 16 + c;
        const float bs = bias[n];
        #pragma unroll
        for (int fm = 0; fm < 2; ++fm) {
            #pragma unroll
            for (int j = 0; j < 4; ++j) {
                const int m = m0 + fm * 16 + 4 * g + j;
                const float v = expf(-fmaxf(acc[fm][fn][j] + bs, 0.f));
                C[(size_t)m * N + n] = f2bf(v);
            }
        }
    }
}

// ---------------------------------------------------------------------------
// x_last scan + x_eff -> Xe bf16 [T,B,I]
// ---------------------------------------------------------------------------
__global__ __launch_bounds__(256) void xeff_scan_kernel(const float* __restrict__ Xall,
                                                        const short* __restrict__ Mall,
                                                        const short* __restrict__ Gx,
                                                        const float* __restrict__ xmean_p,
                                                        short* __restrict__ Xe)
{
    const int bi = blockIdx.x * blockDim.x + threadIdx.x;
    if (bi >= Bb * Ii) return;
    const float xm = xmean_p[0];
    float xl = 0.f;
    for (int t = 0; t < Tt; ++t) {
        const size_t off = (size_t)t * Bb * Ii + bi;
        const float x = Xall[off];
        const float m = bf2f(Mall[off]);
        const float gx = bf2f(Gx[off]);
        if (m > 0.f) xl = x;
        Xe[off] = f2bf(m * x + (1.f - m) * (gx * xl + (1.f - gx) * xm));
    }
}

// ---------------------------------------------------------------------------
// persistent: 256 blocks x 512 thr. block (mt = bid&15, ng = bid>>4):
// rows m0=mt*16..+16; z cols ng*32; r cols 512+ng*32; htilde cols ng*32.
// 2 fence-free flag barriers/step. Stats via IC atomicAdd. BN folded into
// next step's stage (redundant per-block, cheap). Prefetch under barrier polls.
// ---------------------------------------------------------------------------
#define XM_STR 264
#define HP_STR 520
#define RH_STR 520
#define GH_STR 520

__global__ __launch_bounds__(512, 1) void grud_persistent(
    const short* __restrict__ Xe, const short* __restrict__ Ma,
    const short* __restrict__ Ghb,
    const short* __restrict__ Wc1T, const short* __restrict__ Wc2T,
    const float* __restrict__ bias1, const float* __restrict__ b_h,
    const float* __restrict__ bn_g, const float* __restrict__ bn_b,
    const float* __restrict__ Why, const float* __restrict__ bhy,
    short* __restrict__ rhG,          // [256][512] bf16  (atomic-only)
    float* __restrict__ HrawG,        // [256][512] f32   (atomic-only)
    float* __restrict__ PstSum,       // [2][1024] f32    (atomic-only)
    int* __restrict__ flags,          // [256][16] int    (atomic-only)
    float* __restrict__ out_hs, float* __restrict__ out_ys)
{
    const int bid = blockIdx.x, tid = threadIdx.x;
    const int w = tid >> 6, lane = tid & 63, c = lane & 15, g = lane >> 4;
    const int mt = bid & 15, ng = bid >> 4;
    const int m0 = mt * 16;

    __shared__ short sXM[16 * XM_STR];       // 8.4 KB
    __shared__ short sHP[16 * HP_STR];       // 16.6 KB
    __shared__ short sRH[16 * RH_STR];       // 16.6 KB
    __shared__ short sGH[16 * GH_STR];       // 16.6 KB
    __shared__ float sZ[32 * 17];            // 2.2 KB  [localcol][row]
    __shared__ float scratch[1536];          // 6 KB k-split reduce
    __shared__ float sWhy[1024];             // 4 KB
    __shared__ float scs[512], shs[512];     // 4 KB
    __shared__ float ysred[16];

    // ---- constant staging + weight preload (once) ----
    sWhy[tid] = Why[tid]; sWhy[tid + 512] = Why[tid + 512];
    const float bhy0 = bhy[0], bhy1 = bhy[1];

    const int colt = w & 3, kh = w >> 2;             // phase A role
    const int colbaseA = (colt < 2) ? (ng * 32 + colt * 16)
                                    : (512 + ng * 32 + (colt - 2) * 16);
    short8 wA[12];
    {
        const short* bw = Wc1T + (size_t)(colbaseA + c) * 768 + kh * 384 + 8 * g;
        #pragma unroll
        for (int s = 0; s < 12; ++s) wA[s] = *(const short8*)(bw + 32 * s);
    }
    const int colt2 = w & 1, kq = w >> 1;            // phase B role
    const int colbaseB = ng * 32 + colt2 * 16;
    short8 wB[6];
    {
        const short* bw = Wc2T + (size_t)(colbaseB + c) * 768 + kq * 192 + 8 * g;
        #pragma unroll
        for (int s = 0; s < 6; ++s) wB[s] = *(const short8*)(bw + 32 * s);
    }
    // ---- stage [Xe|Ma] for t=0 ----
    {
        const int r = tid >> 5, cu = tid & 31;
        const short* src = (cu < 16)
            ? (Xe + ((size_t)(m0 + r)) * Ii + 8 * cu)
            : (Ma + ((size_t)(m0 + r)) * Ii + 8 * (cu - 16));
        *(short8*)(&sXM[r * XM_STR + 8 * cu]) = *(const short8*)src;
    }
    __syncthreads();

    int ep = 0;
    for (int t = 0; t < Tt; ++t) {
        // ================= stage: BN(t-1) + hp(t) + outputs(t-1) ===========
        if (t > 0) {
            const int parP = (t - 1) & 1;
            {
                const float s1 = ALD_F(&PstSum[parP * 1024 + tid]);
                const float s2 = ALD_F(&PstSum[parP * 1024 + 512 + tid]);
                const float mu = s1 * (1.f / 256.f);
                const float var = fmaxf(s2 * (1.f / 256.f) - mu * mu, 0.f);
                const float sc = bn_g[tid] * rsqrtf(var + EPS_BN);
                scs[tid] = sc; shs[tid] = bn_b[tid] - mu * sc;
            }
            __syncthreads();
            float p0 = 0.f, p1 = 0.f;
            #pragma unroll
            for (int i = 0; i < 8; ++i) {
                const int idx = tid + i * 512;          // u64 index in 16x256
                const int r = idx >> 8, c2 = (idx & 255) * 2;
                union { u64 u; float f[2]; } hv;
                hv.u = ALD_F((const u64*)(HrawG + (size_t)(m0 + r) * Hh + c2));
                const float h0 = fmaf(hv.f[0], scs[c2],     shs[c2]);
                const float h1 = fmaf(hv.f[1], scs[c2 + 1], shs[c2 + 1]);
                // hp = h * gamma_h(t)
                const unsigned gv = *(const unsigned*)(&sGH[r * GH_STR + c2]);
                const unsigned pk = (unsigned)(unsigned short)f2bf(h0 * bf2f((short)(gv & 0xffffu)))
                                  | ((unsigned)(unsigned short)f2bf(h1 * bf2f((short)(gv >> 16))) << 16);
                *(unsigned*)(&sHP[r * HP_STR + c2]) = pk;
                // out_hs slice (cols ng*32..+32)
                if ((c2 >> 5) == ng) {
                    *(f32x2*)(&out_hs[((size_t)(m0 + r) * Tt + (t - 1)) * Hh + c2]) = (f32x2){h0, h1};
                }
                // ys partial for row m0+ng
                if (r == ng) {
                    p0 = fmaf(h0, sWhy[2 * c2],     fmaf(h1, sWhy[2 * c2 + 2], p0));
                    p1 = fmaf(h0, sWhy[2 * c2 + 1], fmaf(h1, sWhy[2 * c2 + 3], p1));
                }
            }
            #pragma unroll
            for (int s = 1; s < 64; s <<= 1) { p0 += __shfl_xor(p0, s); p1 += __shfl_xor(p1, s); }
            if (lane == 0) { ysred[2 * w] = p0; ysred[2 * w + 1] = p1; }
            __syncthreads();
            if (tid == 0) {
                float q0 = 0.f, q1 = 0.f;
                #pragma unroll
                for (int i = 0; i < 8; ++i) { q0 += ysred[2 * i]; q1 += ysred[2 * i + 1]; }
                out_ys[((size_t)(m0 + ng) * Tt + (t - 1)) * Oo + 0] = softplusf_(q0 + bhy0);
                out_ys[((size_t)(m0 + ng) * Tt + (t - 1)) * Oo + 1] = softplusf_(q1 + bhy1);
            }
        } else {
            #pragma unroll
            for (int i = 0; i < 4; ++i) {
                const int e = tid + i * 512;
                const int r = e >> 7, cu = e & 127;
                *(u64*)(&sHP[r * HP_STR + 4 * cu]) = 0ull;
            }
            __syncthreads();
        }

        // ================= Phase A: [Xe|Ma|hp] @ Wc1 (z,r cols) ============
        {
            f32x4 acc = (f32x4){0.f, 0.f, 0.f, 0.f};
            #pragma unroll
            for (int s = 0; s < 12; ++s) {
                const int k = kh * 384 + 32 * s;
                const short8 frag = (k < 256)
                    ? *(const short8*)(&sXM[c * XM_STR + k + 8 * g])
                    : *(const short8*)(&sHP[c * HP_STR + (k - 256) + 8 * g]);
                acc = mfma_bf16(wA[s], frag, acc);
            }
            if (kh == 1) {
                float* sp = scratch + (colt * 64 + lane) * 4;
                sp[0] = acc[0]; sp[1] = acc[1]; sp[2] = acc[2]; sp[3] = acc[3];
            }
            __syncthreads();
            if (kh == 0) {
                const float* sp = scratch + (colt * 64 + lane) * 4;
                acc[0] += sp[0]; acc[1] += sp[1]; acc[2] += sp[2]; acc[3] += sp[3];
                if (colt < 2) {
                    #pragma unroll
                    for (int j = 0; j < 4; ++j) {
                        const int lc = colt * 16 + 4 * g + j;
                        const float v = sigmoidf_(acc[j] + bias1[ng * 32 + lc]);
                        sZ[lc * 17 + c] = v;
                    }
                } else {
                    const int nn0 = ng * 32 + (colt - 2) * 16 + 4 * g;
                    short rh[4];
                    #pragma unroll
                    for (int j = 0; j < 4; ++j) {
                        const float v = sigmoidf_(acc[j] + bias1[512 + nn0 + j]);
                        rh[j] = f2bf(v * bf2f(sHP[c * HP_STR + nn0 + j]));
                    }
                    AST_F((u64*)(rhG + ((size_t)(m0 + c) * Hh + nn0)), *(const u64*)rh);
                }
            }
        }
        // ---- barrier 1 (arrive, prefetch Ghb[t+1], poll) ----
        ep += 1;
        __syncthreads();
        if (tid == 0) AST_F(&flags[bid * 16], ep);
        if (t + 1 < Tt) {
            #pragma unroll
            for (int i = 0; i < 4; ++i) {
                const int e = tid + i * 512;
                const int r = e >> 7, c4 = e & 127;
                const u64 v = *(const u64*)(Ghb + ((size_t)(t + 1) * Bb + m0 + r) * Hh + 4 * c4);
                *(u64*)(&sGH[r * GH_STR + 4 * c4]) = v;
            }
        }
        if (tid < 256) {
            while (__hip_atomic_load(&flags[tid * 16], __ATOMIC_RELAXED, __HIP_MEMORY_SCOPE_AGENT) < ep)
                __builtin_amdgcn_s_sleep(1);
        }
        __syncthreads();

        // ---- stage RH panel (atomic) + zero other-parity stats ----
        #pragma unroll
        for (int i = 0; i < 4; ++i) {
            const int e = tid + i * 512;
            const int r = e >> 7, cu = e & 127;
            const u64 v = ALD_F((const u64*)(rhG + ((size_t)(m0 + r) * Hh + 4 * cu)));
            *(u64*)(&sRH[r * RH_STR + 4 * cu]) = v;
        }
        if (tid < 4) AST_F(&PstSum[((t + 1) & 1) * 1024 + bid * 4 + tid], 0.f);
        __syncthreads();

        // ================= Phase B: [Xe|Ma|RH] @ Wc2 (htilde cols) =========
        {
            f32x4 acc2 = (f32x4){0.f, 0.f, 0.f, 0.f};
            #pragma unroll
            for (int s = 0; s < 6; ++s) {
                const int k = kq * 192 + 32 * s;
                const short8 frag = (k < 256)
                    ? *(const short8*)(&sXM[c * XM_STR + k + 8 * g])
                    : *(const short8*)(&sRH[c * RH_STR + (k - 256) + 8 * g]);
                acc2 = mfma_bf16(wB[s], frag, acc2);
            }
            if (kq > 0) {
                float* sp = scratch + ((colt2 * 3 + kq - 1) * 64 + lane) * 4;
                sp[0] = acc2[0]; sp[1] = acc2[1]; sp[2] = acc2[2]; sp[3] = acc2[3];
            }
            __syncthreads();
            if (kq == 0) {
                #pragma unroll
                for (int qq = 0; qq < 3; ++qq) {
                    const float* sp = scratch + ((colt2 * 3 + qq) * 64 + lane) * 4;
                    acc2[0] += sp[0]; acc2[1] += sp[1]; acc2[2] += sp[2]; acc2[3] += sp[3];
                }
                const int parC = t & 1;
                float hr4[4];
                #pragma unroll
                for (int j = 0; j < 4; ++j) {
                    const int lc = colt2 * 16 + 4 * g + j;
                    const int col = ng * 32 + lc;
                    const float pre = acc2[j] + b_h[col];
                    const float z = sZ[lc * 17 + c];
                    const float hp = bf2f(sHP[c * HP_STR + col]);
                    const float hr = (1.f - z) * hp + z * tanhf(pre);
                    hr4[j] = hr;
                    float sp_ = hr, sq_ = hr * hr;
                    sp_ += __shfl_xor(sp_, 1); sq_ += __shfl_xor(sq_, 1);
                    sp_ += __shfl_xor(sp_, 2); sq_ += __shfl_xor(sq_, 2);
                    sp_ += __shfl_xor(sp_, 4); sq_ += __shfl_xor(sq_, 4);
                    sp_ += __shfl_xor(sp_, 8); sq_ += __shfl_xor(sq_, 8);
                    if (c == 0) {
                        AADD_F(&PstSum[parC * 1024 + col], sp_);
                        AADD_F(&PstSum[parC * 1024 + 512 + col], sq_);
                    }
                }
                const int cb = ng * 32 + colt2 * 16 + 4 * g;
                AST_F((u64*)(HrawG + (size_t)(m0 + c) * Hh + cb),     *(const u64*)&hr4[0]);
                AST_F((u64*)(HrawG + (size_t)(m0 + c) * Hh + cb + 2), *(const u64*)&hr4[2]);
            }
        }
        // ---- barrier 2 (arrive, prefetch Xe/Ma[t+1], poll) ----
        ep += 1;
        __syncthreads();
        if (tid == 0) AST_F(&flags[bid * 16], ep);
        if (t + 1 < Tt) {
            const int r = tid >> 5, cu = tid & 31;
            const short* src = (cu < 16)
                ? (Xe + ((size_t)(t + 1) * Bb + m0 + r) * Ii + 8 * cu)
                : (Ma + ((size_t)(t + 1) * Bb + m0 + r) * Ii + 8 * (cu - 16));
            *(short8*)(&sXM[r * XM_STR + 8 * cu]) = *(const short8*)src;
        }
        if (tid < 256) {
            while (__hip_atomic_load(&flags[tid * 16], __ATOMIC_RELAXED, __HIP_MEMORY_SCOPE_AGENT) < ep)
                __builtin_amdgcn_s_sleep(1);
        }
        __syncthreads();
    }

    // ================= tail: BN + outputs for t = Tt-1 =====================
    {
        const int parP = (Tt - 1) & 1;
        {
            const float s1 = ALD_F(&PstSum[parP * 1024 + tid]);
            const float s2 = ALD_F(&PstSum[parP * 1024 + 512 + tid]);
            const float mu = s1 * (1.f / 256.f);
            const float var = fmaxf(s2 * (1.f / 256.f) - mu * mu, 0.f);
            const float sc = bn_g[tid] * rsqrtf(var + EPS_BN);
            scs[tid] = sc; shs[tid] = bn_b[tid] - mu * sc;
        }
        __syncthreads();
        float p0 = 0.f, p1 = 0.f;
        #pragma unroll
        for (int i = 0; i < 8; ++i) {
            const int idx = tid + i * 512;
            const int r = idx >> 8, c2 = (idx & 255) * 2;
            union { u64 u; float f[2]; } hv;
            hv.u = ALD_F((const u64*)(HrawG + (size_t)(m0 + r) * Hh + c2));
            const float h0 = fmaf(hv.f[0], scs[c2],     shs[c2]);
            const float h1 = fmaf(hv.f[1], scs[c2 + 1], shs[c2 + 1]);
            if ((c2 >> 5) == ng) {
                *(f32x2*)(&out_hs[((size_t)(m0 + r) * Tt + (Tt - 1)) * Hh + c2]) = (f32x2){h0, h1};
            }
            if (r == ng) {
                p0 = fmaf(h0, sWhy[2 * c2],     fmaf(h1, sWhy[2 * c2 + 2], p0));
                p1 = fmaf(h0, sWhy[2 * c2 + 1], fmaf(h1, sWhy[2 * c2 + 3], p1));
            }
        }
        #pragma unroll
        for (int s = 1; s < 64; s <<= 1) { p0 += __shfl_xor(p0, s); p1 += __shfl_xor(p1, s); }
        if (lane == 0) { ysred[2 * w] = p0; ysred[2 * w + 1] = p1; }
        __syncthreads();
        if (tid == 0) {
            float q0 = 0.f, q1 = 0.f;
            #pragma unroll
            for (int i = 0; i < 8; ++i) { q0 += ysred[2 * i]; q1 += ysred[2 * i + 1]; }
            out_ys[((size_t)(m0 + ng) * Tt + (Tt - 1)) * Oo + 0] = softplusf_(q0 + bhy0);
            out_ys[((size_t)(m0 + ng) * Tt + (Tt - 1)) * Oo + 1] = softplusf_(q1 + bhy1);
        }
    }
}

// ---------------------------------------------------------------------------
extern "C" void kernel_launch(void* const* d_in, const int* in_sizes, int n_in,
                              void* d_out, int out_size, void* d_ws, size_t ws_size,
                              hipStream_t stream)
{
    const float* input  = (const float*)d_in[0];
    const float* xmean  = (const float*)d_in[1];
    const float* W_dg_x = (const float*)d_in[2];
    const float* b_dg_x = (const float*)d_in[3];
    const float* W_dg_h = (const float*)d_in[4];
    const float* b_dg_h = (const float*)d_in[5];
    const float* W_xz   = (const float*)d_in[6];
    const float* W_hz   = (const float*)d_in[7];
    const float* W_mz   = (const float*)d_in[8];
    const float* b_z    = (const float*)d_in[9];
    const float* W_xr   = (const float*)d_in[10];
    const float* W_hr   = (const float*)d_in[11];
    const float* W_mr   = (const float*)d_in[12];
    const float* b_r    = (const float*)d_in[13];
    const float* W_xh   = (const float*)d_in[14];
    const float* W_hh   = (const float*)d_in[15];
    const float* W_mh   = (const float*)d_in[16];
    const float* b_h    = (const float*)d_in[17];
    const float* W_hy   = (const float*)d_in[18];
    const float* b_hy   = (const float*)d_in[19];
    const float* bn_g   = (const float*)d_in[20];
    const float* bn_b   = (const float*)d_in[21];

    float* out_ys = (float*)d_out;
    float* out_hs = out_ys + (size_t)Bb * Tt * Oo;

    char* p = (char*)d_ws;
    float* Xall = (float*)p;            p += (size_t)TBr * Ii * 4;
    short* Mall = (short*)p;            p += (size_t)TBr * Ii * 2;
    short* Dall = (short*)p;            p += (size_t)TBr * Ii * 2;
    short* Gxb  = (short*)p;            p += (size_t)TBr * Ii * 2;
    short* Ghb  = (short*)p;            p += (size_t)TBr * Hh * 2;
    short* Xe   = (short*)p;            p += (size_t)TBr * Ii * 2;
    short* Wc1T = (short*)p;            p += (size_t)1024 * 768 * 2;
    short* Wc2T = (short*)p;            p += (size_t)512 * 768 * 2;
    short* WdgxT= (short*)p;            p += (size_t)128 * 128 * 2;
    short* WdghT= (short*)p;            p += (size_t)512 * 128 * 2;
    float* bias1= (float*)p;            p += 1024 * 4;
    short* rhG  = (short*)p;            p += (size_t)Bb * Hh * 2;
    float* HrawG= (float*)p;            p += (size_t)Bb * Hh * 4;
    float* PstSum=(float*)p;            p += 2 * 1024 * 4;
    int*   flags= (int*)p;              p += 256 * 16 * 4;

    hipMemsetAsync(flags, 0, 256 * 16 * 4, stream);
    hipMemsetAsync(PstSum, 0, 2 * 1024 * 4, stream);

    repack_kernel<<<dim3(Tt / 32, Ii / 32, Bb * 3), dim3(32, 32), 0, stream>>>(input, Xall, Mall, Dall);

    {
        const int total = 1024 * 768 + 512 * 768 + 128 * 128 + 512 * 128 + 1024;
        pack_weights_kernel<<<(total + 255) / 256, 256, 0, stream>>>(
            W_dg_x, W_dg_h,
            W_xz, W_hz, W_mz, b_z,
            W_xr, W_hr, W_mr, b_r,
            W_xh, W_hh, W_mh,
            Wc1T, Wc2T, WdgxT, WdghT, bias1);
    }

    gdecay_kernel<<<dim3(TBr / 32, Ii / 64), 64, 0, stream>>>(Dall, WdgxT, b_dg_x, Gxb, Ii);
    gdecay_kernel<<<dim3(TBr / 32, Hh / 64), 64, 0, stream>>>(Dall, WdghT, b_dg_h, Ghb, Hh);

    xeff_scan_kernel<<<(Bb * Ii) / 256, 256, 0, stream>>>(Xall, Mall, Gxb, xmean, Xe);

    grud_persistent<<<256, 512, 0, stream>>>(
        Xe, Mall, Ghb, Wc1T, Wc2T, bias1, b_h, bn_g, bn_b,
        W_hy, b_hy, rhG, HrawG, PstSum, flags, out_hs, out_ys);
}

// Round 8
// 2681.368 us; speedup vs baseline: 10.5203x; 1.0175x over previous
//
#include <hip/hip_runtime.h>
#include <math.h>

#define Bb 256
#define Ii 128
#define Tt 256
#define Hh 512
#define Oo 2
#define TBr (Tt*Bb)
#define EPS_BN 1e-5f

typedef __attribute__((ext_vector_type(8))) short short8;
typedef __attribute__((ext_vector_type(8))) __bf16 bf16x8;
typedef __attribute__((ext_vector_type(4))) float f32x4;
typedef __attribute__((ext_vector_type(2))) float f32x2;
typedef unsigned long long u64;

__device__ __forceinline__ f32x4 mfma_bf16(short8 a, short8 b, f32x4 c) {
    return __builtin_amdgcn_mfma_f32_16x16x32_bf16(
        __builtin_bit_cast(bf16x8, a), __builtin_bit_cast(bf16x8, b), c, 0, 0, 0);
}
__device__ __forceinline__ short f2bf(float f) {
    union { float f; unsigned u; } v; v.f = f;
    unsigned r = (v.u + 0x7FFFu + ((v.u >> 16) & 1u)) >> 16;
    return (short)r;
}
__device__ __forceinline__ float bf2f(short s) {
    union { unsigned u; float f; } v; v.u = ((unsigned)(unsigned short)s) << 16;
    return v.f;
}
__device__ __forceinline__ float sigmoidf_(float x) { return 1.f / (1.f + expf(-x)); }
__device__ __forceinline__ float softplusf_(float x) { return fmaxf(x, 0.f) + log1pf(expf(-fabsf(x))); }

#define ALD_F(p)  __hip_atomic_load((p),  __ATOMIC_RELAXED, __HIP_MEMORY_SCOPE_AGENT)
#define AST_F(p,v) __hip_atomic_store((p), (v), __ATOMIC_RELAXED, __HIP_MEMORY_SCOPE_AGENT)
#define AADD_F(p,v) (void)__hip_atomic_fetch_add((p), (v), __ATOMIC_RELAXED, __HIP_MEMORY_SCOPE_AGENT)

__device__ __forceinline__ short8 ald16(const short* p) {
    union { u64 u[2]; short8 s; } v;
    v.u[0] = ALD_F((const u64*)p);
    v.u[1] = ALD_F((const u64*)(p + 4));
    return v.s;
}
__device__ __forceinline__ u64 pack4bf(float a, float b, float c_, float d) {
    return (u64)(unsigned short)f2bf(a)
         | ((u64)(unsigned short)f2bf(b) << 16)
         | ((u64)(unsigned short)f2bf(c_) << 32)
         | ((u64)(unsigned short)f2bf(d) << 48);
}

// ---------------------------------------------------------------------------
// repack: input [B,3,I,T] fp32 -> time-major X fp32 [T,B,I], M bf16, D bf16
// ---------------------------------------------------------------------------
__global__ __launch_bounds__(1024) void repack_kernel(const float* __restrict__ in,
                                                      float* __restrict__ Xall,
                                                      short* __restrict__ Mall,
                                                      short* __restrict__ Dall)
{
    __shared__ float tile[32][33];
    const int bz = blockIdx.z;
    const int b = bz / 3, cch = bz % 3;
    const int t0 = blockIdx.x * 32, i0 = blockIdx.y * 32;
    const int tx = threadIdx.x, ty = threadIdx.y;
    const float* src = in + ((size_t)b * 3 + cch) * (size_t)Ii * Tt;
    tile[ty][tx] = src[(size_t)(i0 + ty) * Tt + t0 + tx];
    __syncthreads();
    const float v = tile[tx][ty];
    const size_t off = ((size_t)(t0 + ty) * Bb + b) * Ii + i0 + tx;
    if (cch == 0)      Xall[off] = v;
    else if (cch == 1) Mall[off] = f2bf(v);
    else               Dall[off] = f2bf(v);
}

// ---------------------------------------------------------------------------
// pack weights -> bf16 transposed (n-major, k rows) for MFMA fragments
// ---------------------------------------------------------------------------
__global__ __launch_bounds__(256) void pack_weights_kernel(
    const float* __restrict__ W_dg_x, const float* __restrict__ W_dg_h,
    const float* __restrict__ W_xz, const float* __restrict__ W_hz, const float* __restrict__ W_mz, const float* __restrict__ b_z,
    const float* __restrict__ W_xr, const float* __restrict__ W_hr, const float* __restrict__ W_mr, const float* __restrict__ b_r,
    const float* __restrict__ W_xh, const float* __restrict__ W_hh, const float* __restrict__ W_mh,
    short* __restrict__ Wc1T, short* __restrict__ Wc2T,
    short* __restrict__ WdgxT, short* __restrict__ WdghT, float* __restrict__ bias1)
{
    const int idx = blockIdx.x * blockDim.x + threadIdx.x;
    const int n1 = 1024 * 768, n2 = 512 * 768, n3 = 128 * 128, n4 = 512 * 128;
    if (idx < n1) {
        const int n = idx / 768, k = idx % 768;
        const int col = (n < Hh) ? n : (n - Hh);
        const float* Wx = (n < Hh) ? W_xz : W_xr;
        const float* Wm = (n < Hh) ? W_mz : W_mr;
        const float* Wh = (n < Hh) ? W_hz : W_hr;
        float v;
        if (k < Ii)        v = Wx[(size_t)k * Hh + col];
        else if (k < 2*Ii) v = Wm[(size_t)(k - Ii) * Hh + col];
        else               v = Wh[(size_t)(k - 2*Ii) * Hh + col];
        Wc1T[idx] = f2bf(v);
    } else if (idx < n1 + n2) {
        const int j = idx - n1;
        const int n = j / 768, k = j % 768;
        float v;
        if (k < Ii)        v = W_xh[(size_t)k * Hh + n];
        else if (k < 2*Ii) v = W_mh[(size_t)(k - Ii) * Hh + n];
        else               v = W_hh[(size_t)(k - 2*Ii) * Hh + n];
        Wc2T[j] = f2bf(v);
    } else if (idx < n1 + n2 + n3) {
        const int j = idx - n1 - n2;
        const int n = j >> 7, k = j & 127;
        WdgxT[j] = f2bf(W_dg_x[(size_t)k * Ii + n]);
    } else if (idx < n1 + n2 + n3 + n4) {
        const int j = idx - n1 - n2 - n3;
        const int n = j >> 7, k = j & 127;
        WdghT[j] = f2bf(W_dg_h[(size_t)k * Hh + n]);
    } else if (idx < n1 + n2 + n3 + n4 + 1024) {
        const int n = idx - n1 - n2 - n3 - n4;
        bias1[n] = (n < Hh) ? b_z[n] : b_r[n - Hh];
    }
}

// ---------------------------------------------------------------------------
// gdecay: C = bf16(exp(-relu(A @ B + bias)))
// ---------------------------------------------------------------------------
__global__ __launch_bounds__(64) void gdecay_kernel(const short* __restrict__ A,
                                                    const short* __restrict__ BT,
                                                    const float* __restrict__ bias,
                                                    short* __restrict__ C, int N)
{
    const int lane = threadIdx.x;
    const int c = lane & 15, g = lane >> 4;
    const int m0 = blockIdx.x * 32, n0 = blockIdx.y * 64;
    const short* a0 = A + (size_t)(m0 + c) * Ii + 8 * g;
    const short* a1 = a0 + (size_t)16 * Ii;
    const short* bw = BT + (size_t)(n0 + c) * Ii + 8 * g;
    f32x4 acc[2][4];
    #pragma unroll
    for (int i = 0; i < 2; ++i)
        #pragma unroll
        for (int f = 0; f < 4; ++f) acc[i][f] = (f32x4){0.f, 0.f, 0.f, 0.f};
    #pragma unroll
    for (int k0 = 0; k0 < 128; k0 += 32) {
        const short8 av0 = *(const short8*)(a0 + k0);
        const short8 av1 = *(const short8*)(a1 + k0);
        #pragma unroll
        for (int fn = 0; fn < 4; ++fn) {
            const short8 bv = *(const short8*)(bw + (size_t)fn * 16 * Ii + k0);
            acc[0][fn] = mfma_bf16(av0, bv, acc[0][fn]);
            acc[1][fn] = mfma_bf16(av1, bv, acc[1][fn]);
        }
    }
    #pragma unroll
    for (int fn = 0; fn < 4; ++fn) {
        const int n = n0 + fn * 16 + c;
        const float bs = bias[n];
        #pragma unroll
        for (int fm = 0; fm < 2; ++fm) {
            #pragma unroll
            for (int j = 0; j < 4; ++j) {
                const int m = m0 + fm * 16 + 4 * g + j;
                const float v = expf(-fmaxf(acc[fm][fn][j] + bs, 0.f));
                C[(size_t)m * N + n] = f2bf(v);
            }
        }
    }
}

// ---------------------------------------------------------------------------
// x_last scan + x_eff -> Xe bf16 [T,B,I]
// ---------------------------------------------------------------------------
__global__ __launch_bounds__(256) void xeff_scan_kernel(const float* __restrict__ Xall,
                                                        const short* __restrict__ Mall,
                                                        const short* __restrict__ Gx,
                                                        const float* __restrict__ xmean_p,
                                                        short* __restrict__ Xe)
{
    const int bi = blockIdx.x * blockDim.x + threadIdx.x;
    if (bi >= Bb * Ii) return;
    const float xm = xmean_p[0];
    float xl = 0.f;
    for (int t = 0; t < Tt; ++t) {
        const size_t off = (size_t)t * Bb * Ii + bi;
        const float x = Xall[off];
        const float m = bf2f(Mall[off]);
        const float gx = bf2f(Gx[off]);
        if (m > 0.f) xl = x;
        Xe[off] = f2bf(m * x + (1.f - m) * (gx * xl + (1.f - gx) * xm));
    }
}

// ---------------------------------------------------------------------------
// persistent: 256 blocks x 512 thr. block (mt = bid&15, ng = bid>>4):
// rows m0=mt*16..+16; z cols ng*32; r cols 512+ng*32; htilde cols ng*32.
// bar1 = sub-barrier (16 same-mt blocks, gates rhG). bar2 = global (stats).
// HrawG/rhG bf16 via IC atomics; RH read direct from IC in phase B.
// BN stats: mod-3 parity rotation (zeroed in bar1 window).
// ---------------------------------------------------------------------------
#define XM_STR 264
#define HP_STR 520
#define GH_STR 520

__global__ __launch_bounds__(512, 1) void grud_persistent(
    const short* __restrict__ Xe, const short* __restrict__ Ma,
    const short* __restrict__ Ghb,
    const short* __restrict__ Wc1T, const short* __restrict__ Wc2T,
    const float* __restrict__ bias1, const float* __restrict__ b_h,
    const float* __restrict__ bn_g, const float* __restrict__ bn_b,
    const float* __restrict__ Why, const float* __restrict__ bhy,
    short* __restrict__ rhG,          // [256][512] bf16  (atomic-only)
    short* __restrict__ HrawG,        // [256][512] bf16  (atomic-only)
    float* __restrict__ PstSum,       // [3][1024] f32    (atomic-only)
    int* __restrict__ f1,             // [256][16] int    (atomic-only)
    int* __restrict__ f2,             // [256][16] int    (atomic-only)
    float* __restrict__ out_hs, float* __restrict__ out_ys)
{
    const int bid = blockIdx.x, tid = threadIdx.x;
    const int w = tid >> 6, lane = tid & 63, c = lane & 15, g = lane >> 4;
    const int mt = bid & 15, ng = bid >> 4;
    const int m0 = mt * 16;

    __shared__ short sXM[16 * XM_STR];       // 8.4 KB
    __shared__ short sHP[16 * HP_STR];       // 16.6 KB
    __shared__ short sGH[16 * GH_STR];       // 16.6 KB
    __shared__ float sZ[32 * 17];            // 2.2 KB  [localcol][row]
    __shared__ float scratch[1536];          // 6 KB k-split reduce
    __shared__ float sWhy[1024];             // 4 KB
    __shared__ float scs[512], shs[512];     // 4 KB
    __shared__ float ysred[16];

    sWhy[tid] = Why[tid]; sWhy[tid + 512] = Why[tid + 512];
    const float bhy0 = bhy[0], bhy1 = bhy[1];

    const int colt = w & 3, kh = w >> 2;             // phase A role
    const int colbaseA = (colt < 2) ? (ng * 32 + colt * 16)
                                    : (512 + ng * 32 + (colt - 2) * 16);
    short8 wA[12];
    {
        const short* bw = Wc1T + (size_t)(colbaseA + c) * 768 + kh * 384 + 8 * g;
        #pragma unroll
        for (int s = 0; s < 12; ++s) wA[s] = *(const short8*)(bw + 32 * s);
    }
    const int colt2 = w & 1, kq = w >> 1;            // phase B role
    const int colbaseB = ng * 32 + colt2 * 16;
    short8 wB[6];
    {
        const short* bw = Wc2T + (size_t)(colbaseB + c) * 768 + kq * 192 + 8 * g;
        #pragma unroll
        for (int s = 0; s < 6; ++s) wB[s] = *(const short8*)(bw + 32 * s);
    }
    // ---- stage [Xe|Ma] for t=0 ----
    {
        const int r = tid >> 5, cu = tid & 31;
        const short* src = (cu < 16)
            ? (Xe + ((size_t)(m0 + r)) * Ii + 8 * cu)
            : (Ma + ((size_t)(m0 + r)) * Ii + 8 * (cu - 16));
        *(short8*)(&sXM[r * XM_STR + 8 * cu]) = *(const short8*)src;
    }
    __syncthreads();

    for (int t = 0; t < Tt; ++t) {
        // ======= loop-top: [Xe|Ma]-only MFMA partials (no barrier deps) ====
        f32x4 accA = (f32x4){0.f, 0.f, 0.f, 0.f};
        f32x4 accB = (f32x4){0.f, 0.f, 0.f, 0.f};
        if (kh == 0) {
            #pragma unroll
            for (int s = 0; s < 8; ++s)
                accA = mfma_bf16(wA[s],
                    *(const short8*)(&sXM[c * XM_STR + 32 * s + 8 * g]), accA);
        }
        #pragma unroll
        for (int s = 0; s < 6; ++s) {
            const int k = kq * 192 + 32 * s;
            if (k < 256)
                accB = mfma_bf16(wB[s],
                    *(const short8*)(&sXM[c * XM_STR + k + 8 * g]), accB);
        }

        // ======= stage: BN(t-1) scale/shift, hp, out_hs(t-1), ys(t-1) ======
        if (t > 0) {
            const int pR = (t + 2) % 3;               // (t-1) mod 3
            {
                const float s1 = ALD_F(&PstSum[pR * 1024 + tid]);
                const float s2 = ALD_F(&PstSum[pR * 1024 + 512 + tid]);
                const float mu = s1 * (1.f / 256.f);
                const float var = fmaxf(s2 * (1.f / 256.f) - mu * mu, 0.f);
                const float sc = bn_g[tid] * rsqrtf(var + EPS_BN);
                scs[tid] = sc; shs[tid] = bn_b[tid] - mu * sc;
            }
            __syncthreads();
            float p0 = 0.f, p1 = 0.f;
            #pragma unroll
            for (int i = 0; i < 4; ++i) {
                const int idx = tid + i * 512;        // u64 granule in 16x128
                const int r = idx >> 7, c4 = (idx & 127) * 4;
                union { u64 u; unsigned short us[4]; } hv, gv;
                hv.u = ALD_F((const u64*)(HrawG + (size_t)(m0 + r) * Hh + c4));
                gv.u = *(const u64*)(&sGH[r * GH_STR + c4]);
                float h[4];
                #pragma unroll
                for (int j = 0; j < 4; ++j)
                    h[j] = fmaf(bf2f((short)hv.us[j]), scs[c4 + j], shs[c4 + j]);
                *(u64*)(&sHP[r * HP_STR + c4]) =
                    pack4bf(h[0] * bf2f((short)gv.us[0]), h[1] * bf2f((short)gv.us[1]),
                            h[2] * bf2f((short)gv.us[2]), h[3] * bf2f((short)gv.us[3]));
                if ((c4 >> 5) == ng) {
                    *(f32x4*)(&out_hs[((size_t)(m0 + r) * Tt + (t - 1)) * Hh + c4]) =
                        (f32x4){h[0], h[1], h[2], h[3]};
                }
                if (r == ng) {
                    #pragma unroll
                    for (int j = 0; j < 4; ++j) {
                        p0 = fmaf(h[j], sWhy[2 * (c4 + j)], p0);
                        p1 = fmaf(h[j], sWhy[2 * (c4 + j) + 1], p1);
                    }
                }
            }
            #pragma unroll
            for (int s = 1; s < 64; s <<= 1) { p0 += __shfl_xor(p0, s); p1 += __shfl_xor(p1, s); }
            if (lane == 0) { ysred[2 * w] = p0; ysred[2 * w + 1] = p1; }
            __syncthreads();
            if (tid == 0) {
                float q0 = 0.f, q1 = 0.f;
                #pragma unroll
                for (int i = 0; i < 8; ++i) { q0 += ysred[2 * i]; q1 += ysred[2 * i + 1]; }
                out_ys[((size_t)(m0 + ng) * Tt + (t - 1)) * Oo + 0] = softplusf_(q0 + bhy0);
                out_ys[((size_t)(m0 + ng) * Tt + (t - 1)) * Oo + 1] = softplusf_(q1 + bhy1);
            }
        } else {
            #pragma unroll
            for (int i = 0; i < 4; ++i) {
                const int idx = tid + i * 512;
                const int r = idx >> 7, c4 = (idx & 127) * 4;
                *(u64*)(&sHP[r * HP_STR + c4]) = 0ull;
            }
            __syncthreads();
        }

        // ======= Phase A rest: hp part + k-split reduce + epilogue =========
        if (kh == 0) {
            #pragma unroll
            for (int s = 8; s < 12; ++s)
                accA = mfma_bf16(wA[s],
                    *(const short8*)(&sHP[c * HP_STR + (32 * s - 256) + 8 * g]), accA);
        } else {
            #pragma unroll
            for (int s = 0; s < 12; ++s)
                accA = mfma_bf16(wA[s],
                    *(const short8*)(&sHP[c * HP_STR + 128 + 32 * s + 8 * g]), accA);
        }
        if (kh == 1) {
            float* sp = scratch + (colt * 64 + lane) * 4;
            sp[0] = accA[0]; sp[1] = accA[1]; sp[2] = accA[2]; sp[3] = accA[3];
        }
        __syncthreads();
        if (kh == 0) {
            const float* sp = scratch + (colt * 64 + lane) * 4;
            accA[0] += sp[0]; accA[1] += sp[1]; accA[2] += sp[2]; accA[3] += sp[3];
            if (colt < 2) {
                #pragma unroll
                for (int j = 0; j < 4; ++j) {
                    const int lc = colt * 16 + 4 * g + j;
                    const float v = sigmoidf_(accA[j] + bias1[ng * 32 + lc]);
                    sZ[lc * 17 + c] = v;
                }
            } else {
                const int nn0 = ng * 32 + (colt - 2) * 16 + 4 * g;
                float rv[4];
                #pragma unroll
                for (int j = 0; j < 4; ++j) {
                    const float v = sigmoidf_(accA[j] + bias1[512 + nn0 + j]);
                    rv[j] = v * bf2f(sHP[c * HP_STR + nn0 + j]);
                }
                AST_F((u64*)(rhG + ((size_t)(m0 + c) * Hh + nn0)),
                      pack4bf(rv[0], rv[1], rv[2], rv[3]));
            }
        }
        // ---- bar1: sub-barrier over same-mt group (gates rhG) ----
        __syncthreads();
        if (tid == 0) AST_F(&f1[bid * 16], t + 1);
        // window duties: prefetch Ghb(t+1); zero stats parity (t+1)%3
        if (t + 1 < Tt) {
            #pragma unroll
            for (int i = 0; i < 4; ++i) {
                const int idx = tid + i * 512;
                const int r = idx >> 7, c4 = (idx & 127) * 4;
                const u64 v = *(const u64*)(Ghb + ((size_t)(t + 1) * Bb + m0 + r) * Hh + c4);
                *(u64*)(&sGH[r * GH_STR + c4]) = v;
            }
        }
        if (tid < 4) AST_F(&PstSum[((t + 1) % 3) * 1024 + bid * 4 + tid], 0.f);
        if (tid < 16) {
            while (__hip_atomic_load(&f1[(mt + 16 * tid) * 16],
                                     __ATOMIC_RELAXED, __HIP_MEMORY_SCOPE_AGENT) < t + 1)
                __builtin_amdgcn_s_sleep(1);
        }
        __syncthreads();

        // ======= Phase B rest: RH part (direct IC) + reduce + epilogue =====
        #pragma unroll
        for (int s = 0; s < 6; ++s) {
            const int k = kq * 192 + 32 * s;
            if (k >= 256)
                accB = mfma_bf16(wB[s],
                    ald16(rhG + (size_t)(m0 + c) * Hh + (k - 256) + 8 * g), accB);
        }
        if (kq > 0) {
            float* sp = scratch + ((colt2 * 3 + kq - 1) * 64 + lane) * 4;
            sp[0] = accB[0]; sp[1] = accB[1]; sp[2] = accB[2]; sp[3] = accB[3];
        }
        __syncthreads();
        if (kq == 0) {
            #pragma unroll
            for (int qq = 0; qq < 3; ++qq) {
                const float* sp = scratch + ((colt2 * 3 + qq) * 64 + lane) * 4;
                accB[0] += sp[0]; accB[1] += sp[1]; accB[2] += sp[2]; accB[3] += sp[3];
            }
            const int pC = t % 3;
            float hr4[4];
            #pragma unroll
            for (int j = 0; j < 4; ++j) {
                const int lc = colt2 * 16 + 4 * g + j;
                const int col = ng * 32 + lc;
                const float pre = accB[j] + b_h[col];
                const float z = sZ[lc * 17 + c];
                const float hp = bf2f(sHP[c * HP_STR + col]);
                const float hr = (1.f - z) * hp + z * tanhf(pre);
                hr4[j] = hr;
                float sp_ = hr, sq_ = hr * hr;
                sp_ += __shfl_xor(sp_, 1); sq_ += __shfl_xor(sq_, 1);
                sp_ += __shfl_xor(sp_, 2); sq_ += __shfl_xor(sq_, 2);
                sp_ += __shfl_xor(sp_, 4); sq_ += __shfl_xor(sq_, 4);
                sp_ += __shfl_xor(sp_, 8); sq_ += __shfl_xor(sq_, 8);
                if (c == 0) {
                    AADD_F(&PstSum[pC * 1024 + col], sp_);
                    AADD_F(&PstSum[pC * 1024 + 512 + col], sq_);
                }
            }
            const int cb = ng * 32 + colt2 * 16 + 4 * g;
            AST_F((u64*)(HrawG + (size_t)(m0 + c) * Hh + cb),
                  pack4bf(hr4[0], hr4[1], hr4[2], hr4[3]));
        }
        // ---- bar2: global barrier (gates stats + HrawG) ----
        __syncthreads();
        if (tid == 0) AST_F(&f2[bid * 16], t + 1);
        if (t + 1 < Tt) {
            const int r = tid >> 5, cu = tid & 31;
            const short* src = (cu < 16)
                ? (Xe + ((size_t)(t + 1) * Bb + m0 + r) * Ii + 8 * cu)
                : (Ma + ((size_t)(t + 1) * Bb + m0 + r) * Ii + 8 * (cu - 16));
            *(short8*)(&sXM[r * XM_STR + 8 * cu]) = *(const short8*)src;
        }
        if (tid < 256) {
            while (__hip_atomic_load(&f2[tid * 16],
                                     __ATOMIC_RELAXED, __HIP_MEMORY_SCOPE_AGENT) < t + 1)
                __builtin_amdgcn_s_sleep(1);
        }
        __syncthreads();
    }

    // ================= tail: BN + outputs for t = Tt-1 =====================
    {
        const int pR = (Tt - 1) % 3;
        {
            const float s1 = ALD_F(&PstSum[pR * 1024 + tid]);
            const float s2 = ALD_F(&PstSum[pR * 1024 + 512 + tid]);
            const float mu = s1 * (1.f / 256.f);
            const float var = fmaxf(s2 * (1.f / 256.f) - mu * mu, 0.f);
            const float sc = bn_g[tid] * rsqrtf(var + EPS_BN);
            scs[tid] = sc; shs[tid] = bn_b[tid] - mu * sc;
        }
        __syncthreads();
        float p0 = 0.f, p1 = 0.f;
        #pragma unroll
        for (int i = 0; i < 4; ++i) {
            const int idx = tid + i * 512;
            const int r = idx >> 7, c4 = (idx & 127) * 4;
            union { u64 u; unsigned short us[4]; } hv;
            hv.u = ALD_F((const u64*)(HrawG + (size_t)(m0 + r) * Hh + c4));
            float h[4];
            #pragma unroll
            for (int j = 0; j < 4; ++j)
                h[j] = fmaf(bf2f((short)hv.us[j]), scs[c4 + j], shs[c4 + j]);
            if ((c4 >> 5) == ng) {
                *(f32x4*)(&out_hs[((size_t)(m0 + r) * Tt + (Tt - 1)) * Hh + c4]) =
                    (f32x4){h[0], h[1], h[2], h[3]};
            }
            if (r == ng) {
                #pragma unroll
                for (int j = 0; j < 4; ++j) {
                    p0 = fmaf(h[j], sWhy[2 * (c4 + j)], p0);
                    p1 = fmaf(h[j], sWhy[2 * (c4 + j) + 1], p1);
                }
            }
        }
        #pragma unroll
        for (int s = 1; s < 64; s <<= 1) { p0 += __shfl_xor(p0, s); p1 += __shfl_xor(p1, s); }
        if (lane == 0) { ysred[2 * w] = p0; ysred[2 * w + 1] = p1; }
        __syncthreads();
        if (tid == 0) {
            float q0 = 0.f, q1 = 0.f;
            #pragma unroll
            for (int i = 0; i < 8; ++i) { q0 += ysred[2 * i]; q1 += ysred[2 * i + 1]; }
            out_ys[((size_t)(m0 + ng) * Tt + (Tt - 1)) * Oo + 0] = softplusf_(q0 + bhy0);
            out_ys[((size_t)(m0 + ng) * Tt + (Tt - 1)) * Oo + 1] = softplusf_(q1 + bhy1);
        }
    }
}

// ---------------------------------------------------------------------------
extern "C" void kernel_launch(void* const* d_in, const int* in_sizes, int n_in,
                              void* d_out, int out_size, void* d_ws, size_t ws_size,
                              hipStream_t stream)
{
    const float* input  = (const float*)d_in[0];
    const float* xmean  = (const float*)d_in[1];
    const float* W_dg_x = (const float*)d_in[2];
    const float* b_dg_x = (const float*)d_in[3];
    const float* W_dg_h = (const float*)d_in[4];
    const float* b_dg_h = (const float*)d_in[5];
    const float* W_xz   = (const float*)d_in[6];
    const float* W_hz   = (const float*)d_in[7];
    const float* W_mz   = (const float*)d_in[8];
    const float* b_z    = (const float*)d_in[9];
    const float* W_xr   = (const float*)d_in[10];
    const float* W_hr   = (const float*)d_in[11];
    const float* W_mr   = (const float*)d_in[12];
    const float* b_r    = (const float*)d_in[13];
    const float* W_xh   = (const float*)d_in[14];
    const float* W_hh   = (const float*)d_in[15];
    const float* W_mh   = (const float*)d_in[16];
    const float* b_h    = (const float*)d_in[17];
    const float* W_hy   = (const float*)d_in[18];
    const float* b_hy   = (const float*)d_in[19];
    const float* bn_g   = (const float*)d_in[20];
    const float* bn_b   = (const float*)d_in[21];

    float* out_ys = (float*)d_out;
    float* out_hs = out_ys + (size_t)Bb * Tt * Oo;

    char* p = (char*)d_ws;
    float* Xall = (float*)p;            p += (size_t)TBr * Ii * 4;
    short* Mall = (short*)p;            p += (size_t)TBr * Ii * 2;
    short* Dall = (short*)p;            p += (size_t)TBr * Ii * 2;
    short* Gxb  = (short*)p;            p += (size_t)TBr * Ii * 2;
    short* Ghb  = (short*)p;            p += (size_t)TBr * Hh * 2;
    short* Xe   = (short*)p;            p += (size_t)TBr * Ii * 2;
    short* Wc1T = (short*)p;            p += (size_t)1024 * 768 * 2;
    short* Wc2T = (short*)p;            p += (size_t)512 * 768 * 2;
    short* WdgxT= (short*)p;            p += (size_t)128 * 128 * 2;
    short* WdghT= (short*)p;            p += (size_t)512 * 128 * 2;
    float* bias1= (float*)p;            p += 1024 * 4;
    short* rhG  = (short*)p;            p += (size_t)Bb * Hh * 2;
    short* HrawG= (short*)p;            p += (size_t)Bb * Hh * 2;
    float* PstSum=(float*)p;            p += 3 * 1024 * 4;
    int*   f1   = (int*)p;              p += 256 * 16 * 4;
    int*   f2   = (int*)p;              p += 256 * 16 * 4;

    hipMemsetAsync(f1, 0, 256 * 16 * 4, stream);
    hipMemsetAsync(f2, 0, 256 * 16 * 4, stream);
    hipMemsetAsync(PstSum, 0, 3 * 1024 * 4, stream);

    repack_kernel<<<dim3(Tt / 32, Ii / 32, Bb * 3), dim3(32, 32), 0, stream>>>(input, Xall, Mall, Dall);

    {
        const int total = 1024 * 768 + 512 * 768 + 128 * 128 + 512 * 128 + 1024;
        pack_weights_kernel<<<(total + 255) / 256, 256, 0, stream>>>(
            W_dg_x, W_dg_h,
            W_xz, W_hz, W_mz, b_z,
            W_xr, W_hr, W_mr, b_r,
            W_xh, W_hh, W_mh,
            Wc1T, Wc2T, WdgxT, WdghT, bias1);
    }

    gdecay_kernel<<<dim3(TBr / 32, Ii / 64), 64, 0, stream>>>(Dall, WdgxT, b_dg_x, Gxb, Ii);
    gdecay_kernel<<<dim3(TBr / 32, Hh / 64), 64, 0, stream>>>(Dall, WdghT, b_dg_h, Ghb, Hh);

    xeff_scan_kernel<<<(Bb * Ii) / 256, 256, 0, stream>>>(Xall, Mall, Gxb, xmean, Xe);

    grud_persistent<<<256, 512, 0, stream>>>(
        Xe, Mall, Ghb, Wc1T, Wc2T, bias1, b_h, bn_g, bn_b,
        W_hy, b_hy, rhG, HrawG, PstSum, f1, f2, out_hs, out_ys);
}